// Round 1
// 530.247 us; speedup vs baseline: 1.0721x; 1.0721x over previous
//
#include <hip/hip_runtime.h>
#include <hip/hip_bf16.h>

typedef __attribute__((ext_vector_type(8))) short short8;
typedef __attribute__((ext_vector_type(4))) float floatx4;
typedef __attribute__((ext_vector_type(8))) int intx8;

#define AS_GLOBAL(p) ((const __attribute__((address_space(1))) void*)(p))
#define AS_LOCAL(p)  ((__attribute__((address_space(3))) void*)(p))

__device__ __forceinline__ float b2f(unsigned short u) {
    union { unsigned int u; float f; } c; c.u = ((unsigned int)u) << 16; return c.f;
}
__device__ __forceinline__ unsigned short f2b(float f) {
    union { float f; unsigned int u; } c; c.f = f;
    unsigned int u = c.u;
    unsigned int r = (u + 0x7fffu + ((u >> 16) & 1u)) >> 16;
    return (unsigned short)r;
}
__device__ __forceinline__ unsigned char f2fp8(float v) {
    return (unsigned char)(__builtin_amdgcn_cvt_pk_fp8_f32(v, v, 0, false) & 0xff);
}

// ---------------- cast x: fp32 -> bf16 AND fp8(e4m3) in one pass ----------------
__global__ __launch_bounds__(256) void cast_x(
    const float* __restrict__ in, unsigned short* __restrict__ xbf,
    unsigned int* __restrict__ xf8, int n4) {
    int i = blockIdx.x * 256 + threadIdx.x;
    if (i >= n4) return;
    float4 v = ((const float4*)in)[i];
    ushort4 o;
    o.x = f2b(v.x); o.y = f2b(v.y); o.z = f2b(v.z); o.w = f2b(v.w);
    ((ushort4*)xbf)[i] = o;
    int p = __builtin_amdgcn_cvt_pk_fp8_f32(v.x, v.y, 0, false);
    p = __builtin_amdgcn_cvt_pk_fp8_f32(v.z, v.w, p, true);
    xf8[i] = (unsigned int)p;
}

// ---------------- transpose fp32 [R][C] -> bf16 [C][R] (weights, small) ----------------
__global__ __launch_bounds__(256) void transpose_f32_bf16(
    const float* __restrict__ in, unsigned short* __restrict__ out, int R, int C) {
    __shared__ float t[32][33];
    int c0 = blockIdx.x * 32, r0 = blockIdx.y * 32;
    int tx = threadIdx.x, ty = threadIdx.y;
#pragma unroll
    for (int k = 0; k < 32; k += 8)
        t[ty + k][tx] = in[(size_t)(r0 + ty + k) * C + c0 + tx];
    __syncthreads();
#pragma unroll
    for (int k = 0; k < 32; k += 8)
        out[(size_t)(c0 + ty + k) * R + r0 + tx] = f2b(t[tx][ty + k]);
}

// ---------------- transpose Wqkv[:, :2048] fp32 [1024][3072] -> fp8 [2048][1024] ----------------
__global__ __launch_bounds__(256) void transpose_f32_fp8_qk(
    const float* __restrict__ in, unsigned char* __restrict__ out) {
    __shared__ float t[32][33];
    int c0 = blockIdx.x * 32, r0 = blockIdx.y * 32;   // c: 0..2048, r: 0..1024
    int tx = threadIdx.x, ty = threadIdx.y;
#pragma unroll
    for (int k = 0; k < 32; k += 8)
        t[ty + k][tx] = in[(size_t)(r0 + ty + k) * 3072 + c0 + tx];
    __syncthreads();
#pragma unroll
    for (int k = 0; k < 32; k += 8)
        out[(size_t)(c0 + ty + k) * 1024 + r0 + tx] = f2fp8(t[tx][ty + k]);
}

// ---------------- Wv slice: fp32 Wqkv[:,2048:3072] -> bf16 [1024][1024] ----------------
__global__ __launch_bounds__(256) void cast_wv(
    const float* __restrict__ in, unsigned short* __restrict__ out) {
    int i = blockIdx.x * 256 + threadIdx.x;   // over 262144 float4s
    int d = i >> 8, rem = (i & 255) * 4;
    float4 v = *(const float4*)&in[(size_t)d * 3072 + 2048 + rem];
    ushort4 o;
    o.x = f2b(v.x); o.y = f2b(v.y); o.z = f2b(v.z); o.w = f2b(v.w);
    *(ushort4*)&out[(size_t)d * 1024 + rem] = o;
}

// ---------------- bvo[e] = sum_h bqkv[2048+h]*WoT[e][h] + bout[e] ----------------
__global__ __launch_bounds__(256) void bvo_kernel(
    const unsigned short* __restrict__ WoT, const float* __restrict__ bqkv,
    const float* __restrict__ bout, float* __restrict__ bvo) {
    int wv = threadIdx.x >> 6, lane = threadIdx.x & 63;
    int e = blockIdx.x * 4 + wv;
    const unsigned short* row = WoT + (size_t)e * 1024;
    float s = 0.f;
    for (int h = lane; h < 1024; h += 64) s += b2f(row[h]) * bqkv[2048 + h];
#pragma unroll
    for (int o = 32; o; o >>= 1) s += __shfl_xor(s, o);
    if (lane == 0) bvo[e] = s + bout[e];
}

// ---------------- double softmax + mask, in place on S (bf16) ----------------
__global__ __launch_bounds__(256) void softmax2_kernel(
    unsigned short* __restrict__ S, const int* __restrict__ mask) {
    const int N = 2048;
    int wv = threadIdx.x >> 6, lane = threadIdx.x & 63;
    size_t row = (size_t)blockIdx.x * 4 + wv;
    unsigned short* srow = S + row * N;
    const int* mrow = mask + row * N;

    float e1[32];
    float l = 0.f;
#pragma unroll
    for (int i = 0; i < 4; ++i) {
        uint4 raw = ((const uint4*)srow)[lane + 64 * i];
        unsigned v[4] = { raw.x, raw.y, raw.z, raw.w };
#pragma unroll
        for (int j = 0; j < 4; ++j) {
            float a = b2f((unsigned short)(v[j] & 0xffff));
            float bb = b2f((unsigned short)(v[j] >> 16));
            float ea = __expf(a), eb = __expf(bb);
            e1[i * 8 + 2 * j] = ea; e1[i * 8 + 2 * j + 1] = eb;
            l += ea + eb;
        }
    }
#pragma unroll
    for (int o = 32; o; o >>= 1) l += __shfl_xor(l, o);
    float invl = 1.0f / l;

    float e2[32];
    float z = 0.f;
#pragma unroll
    for (int i = 0; i < 4; ++i) {
        uint4 m0 = ((const uint4*)mrow)[2 * (lane + 64 * i)];
        uint4 m1 = ((const uint4*)mrow)[2 * (lane + 64 * i) + 1];
        int mk[8] = { (int)m0.x, (int)m0.y, (int)m0.z, (int)m0.w,
                      (int)m1.x, (int)m1.y, (int)m1.z, (int)m1.w };
#pragma unroll
        for (int j = 0; j < 8; ++j) {
            float w1 = e1[i * 8 + j] * invl;
            float e = mk[j] ? __expf(w1) : 0.0f;
            e2[i * 8 + j] = e; z += e;
        }
    }
#pragma unroll
    for (int o = 32; o; o >>= 1) z += __shfl_xor(z, o);
    float invz = (z > 0.f) ? 1.0f / z : 0.0f;
    float fallback = 1.0f / N;
#pragma unroll
    for (int i = 0; i < 4; ++i) {
        float p[8];
#pragma unroll
        for (int j = 0; j < 8; ++j)
            p[j] = (z > 0.f) ? e2[i * 8 + j] * invz : fallback;
        uint4 o;
        o.x = (unsigned)f2b(p[0]) | ((unsigned)f2b(p[1]) << 16);
        o.y = (unsigned)f2b(p[2]) | ((unsigned)f2b(p[3]) << 16);
        o.z = (unsigned)f2b(p[4]) | ((unsigned)f2b(p[5]) << 16);
        o.w = (unsigned)f2b(p[6]) | ((unsigned)f2b(p[7]) << 16);
        ((uint4*)srow)[lane + 64 * i] = o;
    }
}

// ---------------- bf16 GEMM, B in [n][k] layout, m97-style ----------------
// 1D grid + bijective XCD-chunk swizzle (m204): XCD k gets contiguous work chunk
// so panel/batch working sets pin to one XCD's L2 instead of being replicated 8x.
// OUT: 0 = bf16 C[m][n], 1 = f32 C[m][n], 2 = bf16 transposed VpT-write:
//      C[batch][n][m] with batch = tm0>>11 (M is flattened tokens, 2048/batch).
template <int TAG, bool BIAS, int OUT, int XS, int YS>
__global__ __launch_bounds__(256) void gemm_bt(
    const unsigned short* __restrict__ A, int ldA, long long strideA,
    const unsigned short* __restrict__ B, int ldB, long long strideB,
    void* __restrict__ C, int ldC, long long strideC,
    const float* __restrict__ bias, float scale, int K) {
    __shared__ __align__(16) unsigned short lds[2 * 128 * 64];
    unsigned short* At = lds;
    unsigned short* Bt = lds + 128 * 64;

    // XCD swizzle: nwg % 8 == 0 for all launches (bijective chunked remap)
    unsigned flat = blockIdx.x;
    unsigned wg = (flat & 7u) * (gridDim.x >> 3) + (flat >> 3);
    int bx = wg & ((1u << XS) - 1u);
    int by = (wg >> XS) & ((1u << YS) - 1u);
    int bz = wg >> (XS + YS);

    const unsigned short* Ab = A + (size_t)bz * strideA;
    const unsigned short* Bb = B + (size_t)bz * strideB;
    int tn0 = bx * 128;
    int tm0 = by * 128;
    int tid = threadIdx.x;
    int wave = tid >> 6, lane = tid & 63;
    int lm = lane & 15, q = lane >> 4;
    int wm = (wave >> 1) * 64, wn = (wave & 1) * 64;

    int srow = lane >> 3;
    int sblk = lane & 7;

    floatx4 acc[4][4] = {};

    for (int k0 = 0; k0 < K; k0 += 64) {
        __syncthreads();
#pragma unroll
        for (int i = 0; i < 4; ++i) {
            int chunk = wave * 4 + i;
            int r = chunk * 8 + srow;
            int blk = sblk ^ (r & 7);
            const unsigned short* ga = Ab + (size_t)(tm0 + r) * ldA + (k0 + blk * 8);
            __builtin_amdgcn_global_load_lds(AS_GLOBAL(ga), AS_LOCAL(At + chunk * 512), 16, 0, 0);
            const unsigned short* gb = Bb + (size_t)(tn0 + r) * ldB + (k0 + blk * 8);
            __builtin_amdgcn_global_load_lds(AS_GLOBAL(gb), AS_LOCAL(Bt + chunk * 512), 16, 0, 0);
        }
        __syncthreads();
#pragma unroll
        for (int kk = 0; kk < 2; ++kk) {
            short8 af[4], bf[4];
#pragma unroll
            for (int mt = 0; mt < 4; ++mt) {
                int r = wm + mt * 16 + lm;
                af[mt] = *(const short8*)(At + r * 64 + (((kk * 4 + q) ^ (r & 7)) * 8));
            }
#pragma unroll
            for (int nt = 0; nt < 4; ++nt) {
                int r = wn + nt * 16 + lm;
                bf[nt] = *(const short8*)(Bt + r * 64 + (((kk * 4 + q) ^ (r & 7)) * 8));
            }
#pragma unroll
            for (int mt = 0; mt < 4; ++mt)
#pragma unroll
                for (int nt = 0; nt < 4; ++nt)
                    acc[mt][nt] = __builtin_amdgcn_mfma_f32_16x16x32_bf16(
                        af[mt], bf[nt], acc[mt][nt], 0, 0, 0);
        }
    }

    float biasv[4];
#pragma unroll
    for (int nt = 0; nt < 4; ++nt)
        biasv[nt] = BIAS ? bias[tn0 + wn + nt * 16 + lm] : 0.0f;

    if (OUT == 2) {
        // Transposed epilogue: stash C-tile into the (now free) 32 KB staging LDS
        // as [n][m] with element-XOR swizzle (keeps 16B chunks, ~2-way banks),
        // then store coalesced rows of VpT. Kills the separate transpose kernel.
        __syncthreads();
        unsigned short* T = lds;   // [128][128] bf16, col = m ^ ((n&15)<<3)
#pragma unroll
        for (int mt = 0; mt < 4; ++mt)
#pragma unroll
            for (int nt = 0; nt < 4; ++nt) {
                int n = wn + nt * 16 + lm;
                int m0 = wm + mt * 16 + q * 4;
                int col = m0 ^ ((n & 15) << 3);
                ushort4 pv;
                float v0 = acc[mt][nt][0] * scale; if (BIAS) v0 += biasv[nt];
                float v1 = acc[mt][nt][1] * scale; if (BIAS) v1 += biasv[nt];
                float v2 = acc[mt][nt][2] * scale; if (BIAS) v2 += biasv[nt];
                float v3 = acc[mt][nt][3] * scale; if (BIAS) v3 += biasv[nt];
                pv.x = f2b(v0); pv.y = f2b(v1); pv.z = f2b(v2); pv.w = f2b(v3);
                *(ushort4*)&T[n * 128 + col] = pv;
            }
        __syncthreads();
        unsigned short* Cb = (unsigned short*)C + (size_t)(tm0 >> 11) * strideC + (tm0 & 2047);
#pragma unroll
        for (int r8 = 0; r8 < 8; ++r8) {
            int idx = tid + 256 * r8;        // 0..2047 over 128 rows x 16 chunks
            int d = idx >> 4, c = idx & 15;
            int cs = (c ^ (d & 15)) << 3;    // inverse of the write swizzle
            short8 v = *(const short8*)&T[d * 128 + cs];
            *(short8*)&Cb[(size_t)(tn0 + d) * ldC + c * 8] = v;
        }
        return;
    }

#pragma unroll
    for (int mt = 0; mt < 4; ++mt) {
#pragma unroll
        for (int nt = 0; nt < 4; ++nt) {
            int gm = tm0 + wm + mt * 16 + q * 4;
            int gn = tn0 + wn + nt * 16 + lm;
#pragma unroll
            for (int r = 0; r < 4; ++r) {
                float v = acc[mt][nt][r] * scale;
                if (BIAS) v += biasv[nt];
                size_t idx = (size_t)bz * strideC + (size_t)(gm + r) * ldC + gn;
                if (OUT == 1) ((float*)C)[idx] = v;
                else          ((unsigned short*)C)[idx] = f2b(v);
            }
        }
    }
}

// ---------------- fp8(e4m3) GEMM via mfma_scale 16x16x128, unit scales ----------------
// Same m97 structure + XCD-chunk swizzle as gemm_bt.
template <int TAG, bool BIAS, bool OUTFP8, int XS, int YS>
__global__ __launch_bounds__(256) void gemm_f8_bt(
    const unsigned char* __restrict__ A, int ldA, long long strideA,
    const unsigned char* __restrict__ B, int ldB, long long strideB,
    void* __restrict__ C, int ldC, long long strideC,
    const float* __restrict__ bias, float scale, int K) {
    __shared__ __align__(16) unsigned char lds[2 * 128 * 128];
    unsigned char* At = lds;
    unsigned char* Bt = lds + 128 * 128;

    unsigned flat = blockIdx.x;
    unsigned wg = (flat & 7u) * (gridDim.x >> 3) + (flat >> 3);
    int bx = wg & ((1u << XS) - 1u);
    int by = (wg >> XS) & ((1u << YS) - 1u);
    int bz = wg >> (XS + YS);

    const unsigned char* Ab = A + (size_t)bz * strideA;
    const unsigned char* Bb = B + (size_t)bz * strideB;
    int tn0 = bx * 128;
    int tm0 = by * 128;
    int tid = threadIdx.x;
    int wave = tid >> 6, lane = tid & 63;
    int lm = lane & 15, q = lane >> 4;
    int q2 = q * 2;
    int wm = (wave >> 1) * 64, wn = (wave & 1) * 64;

    int srow = lane >> 3;
    int sblk = lane & 7;

    floatx4 acc[4][4] = {};

    for (int k0 = 0; k0 < K; k0 += 128) {
        __syncthreads();
#pragma unroll
        for (int i = 0; i < 4; ++i) {
            int chunk = wave * 4 + i;
            int r = chunk * 8 + srow;
            int blk = sblk ^ (r & 7);
            const unsigned char* ga = Ab + (size_t)(tm0 + r) * ldA + (k0 + blk * 16);
            __builtin_amdgcn_global_load_lds(AS_GLOBAL(ga), AS_LOCAL(At + chunk * 1024), 16, 0, 0);
            const unsigned char* gb = Bb + (size_t)(tn0 + r) * ldB + (k0 + blk * 16);
            __builtin_amdgcn_global_load_lds(AS_GLOBAL(gb), AS_LOCAL(Bt + chunk * 1024), 16, 0, 0);
        }
        __syncthreads();
        intx8 af[4], bf[4];
#pragma unroll
        for (int mt = 0; mt < 4; ++mt) {
            int r = wm + mt * 16 + lm;
            const unsigned char* base = At + r * 128;
            int4 lo = *(const int4*)(base + ((q2 ^ (r & 7)) << 4));
            int4 hi = *(const int4*)(base + (((q2 + 1) ^ (r & 7)) << 4));
            af[mt][0] = lo.x; af[mt][1] = lo.y; af[mt][2] = lo.z; af[mt][3] = lo.w;
            af[mt][4] = hi.x; af[mt][5] = hi.y; af[mt][6] = hi.z; af[mt][7] = hi.w;
        }
#pragma unroll
        for (int nt = 0; nt < 4; ++nt) {
            int r = wn + nt * 16 + lm;
            const unsigned char* base = Bt + r * 128;
            int4 lo = *(const int4*)(base + ((q2 ^ (r & 7)) << 4));
            int4 hi = *(const int4*)(base + (((q2 + 1) ^ (r & 7)) << 4));
            bf[nt][0] = lo.x; bf[nt][1] = lo.y; bf[nt][2] = lo.z; bf[nt][3] = lo.w;
            bf[nt][4] = hi.x; bf[nt][5] = hi.y; bf[nt][6] = hi.z; bf[nt][7] = hi.w;
        }
#pragma unroll
        for (int mt = 0; mt < 4; ++mt)
#pragma unroll
            for (int nt = 0; nt < 4; ++nt)
                acc[mt][nt] = __builtin_amdgcn_mfma_scale_f32_16x16x128_f8f6f4(
                    af[mt], bf[nt], acc[mt][nt], 0, 0,
                    0, 0x7f7f7f7f, 0, 0x7f7f7f7f);
    }

    float biasv[4];
#pragma unroll
    for (int nt = 0; nt < 4; ++nt)
        biasv[nt] = BIAS ? bias[tn0 + wn + nt * 16 + lm] : 0.0f;
#pragma unroll
    for (int mt = 0; mt < 4; ++mt) {
#pragma unroll
        for (int nt = 0; nt < 4; ++nt) {
            int gm = tm0 + wm + mt * 16 + q * 4;
            int gn = tn0 + wn + nt * 16 + lm;
#pragma unroll
            for (int r = 0; r < 4; ++r) {
                float v = acc[mt][nt][r] * scale;
                if (BIAS) v += biasv[nt];
                size_t idx = (size_t)bz * strideC + (size_t)(gm + r) * ldC + gn;
                if (OUTFP8) ((unsigned char*)C)[idx] = f2fp8(v);
                else        ((unsigned short*)C)[idx] = f2b(v);
            }
        }
    }
}

extern "C" void kernel_launch(void* const* d_in, const int* in_sizes, int n_in,
                              void* d_out, int out_size, void* d_ws, size_t ws_size,
                              hipStream_t stream) {
    const float* x    = (const float*)d_in[0];   // [8,2048,1024]
    const int*   mask = (const int*)d_in[1];     // [8,2048,2048]
    const float* Wqkv = (const float*)d_in[2];   // [1024,3072]
    const float* bqkv = (const float*)d_in[3];   // [3072]
    const float* Wout = (const float*)d_in[4];   // [1024,1024]
    const float* bout = (const float*)d_in[5];   // [1024]
    float* out = (float*)d_out;                  // [8,2048,1024]

    char* w = (char*)d_ws;
    unsigned short* x_bf  = (unsigned short*)(w);              // 33,554,432
    unsigned char*  x_f8  = (unsigned char*)(w + 33554432);    // 16,777,216
    unsigned char*  QKf8  = (unsigned char*)(w + 50331648);    // 33,554,432  [16384][2048]: Q cols 0..1023, K cols 1024..2047
    unsigned short* VpT   = (unsigned short*)(w + 117440512);  // 33,554,432  [8][1024][2048]
    unsigned short* S     = (unsigned short*)(w + 150994944);  // 67,108,864
    unsigned char*  WqkT8 = (unsigned char*)(w + 218103808);   //  2,097,152
    unsigned short* WoT   = (unsigned short*)(w + 220200960);  //  2,097,152
    unsigned short* Wv_bf = (unsigned short*)(w + 222298112);  //  2,097,152
    unsigned short* WvoT  = (unsigned short*)(w + 224395264);  //  2,097,152
    float*          bvo   = (float*)(w + 226492416);           //      4,096  -> 226.5 MB total

    // 1) input casts / weight prep
    cast_x<<<16384, 256, 0, stream>>>(x, x_bf, (unsigned int*)x_f8, 4194304);
    transpose_f32_fp8_qk<<<dim3(64, 32), dim3(32, 8), 0, stream>>>(Wqkv, WqkT8);
    transpose_f32_bf16<<<dim3(32, 32), dim3(32, 8), 0, stream>>>(Wout, WoT, 1024, 1024);
    cast_wv<<<1024, 256, 0, stream>>>(Wqkv, Wv_bf);
    bvo_kernel<<<256, 256, 0, stream>>>(WoT, bqkv, bout, bvo);

    // 2) WvoT = (Wv @ Wout)^T : C[e][d] = sum_h WoT[e][h] * Wv[d][h]   (grid 8x8 -> 64)
    gemm_bt<4, false, 0, 3, 3><<<64, 256, 0, stream>>>(
        WoT, 1024, 0, Wv_bf, 1024, 0, WvoT, 1024, 0, nullptr, 1.0f, 1024);

    // 3) QK projection in fp8: [16384][2048] = x_f8 @ WqkT8^T + bqkv[0:2048]
    //    grid 16x128 -> 2048; XCD k gets M-chunk [16k,16k+16) tiles; WqkT8 (2MB) L2-resident
    gemm_f8_bt<0, true, true, 4, 7><<<2048, 256, 0, stream>>>(
        x_f8, 1024, 0, WqkT8, 1024, 0, QKf8, 2048, 0, bqkv, 1.0f, 1024);

    // 4) V'^T = (x @ Wvo + bvo)^T, transposed epilogue writes VpT [8][1024][2048] directly
    //    grid 8x128 -> 1024 (OUT=2: batch = tm0>>11)
    gemm_bt<5, true, 2, 3, 7><<<1024, 256, 0, stream>>>(
        x_bf, 1024, 0, WvoT, 1024, 0, VpT, 2048, 1024LL * 2048, bvo, 1.0f, 1024);

    // 5) S = Q @ K^T / sqrt(D) in fp8 -> bf16 [8][2048][2048]
    //    grid 16x16x8 -> 2048; XCD k <-> batch k (256 blocks/batch)
    gemm_f8_bt<1, false, false, 4, 4><<<2048, 256, 0, stream>>>(
        QKf8, 2048, 2048LL * 2048, QKf8 + 1024, 2048, 2048LL * 2048,
        S, 2048, 2048LL * 2048, nullptr, 0.03125f, 1024);

    // 6) softmax -> mask -> softmax, in place
    softmax2_kernel<<<4096, 256, 0, stream>>>(S, mask);

    // 7) out = P @ V' -> fp32 d_out
    //    grid 8x16x8 -> 1024; XCD k <-> batch k (128 blocks/batch, x-inner A-panel reuse)
    gemm_bt<2, false, 1, 3, 4><<<1024, 256, 0, stream>>>(
        S, 2048, 2048LL * 2048, VpT, 2048, 1024LL * 2048,
        out, 1024, 2048LL * 1024, nullptr, 1.0f, 2048);
}

// Round 4
// 500.286 us; speedup vs baseline: 1.1363x; 1.0599x over previous
//
#include <hip/hip_runtime.h>
#include <hip/hip_bf16.h>

typedef __attribute__((ext_vector_type(8))) short short8;
typedef __attribute__((ext_vector_type(4))) float floatx4;
typedef __attribute__((ext_vector_type(8))) int intx8;

#define AS_GLOBAL(p) ((const __attribute__((address_space(1))) void*)(p))
#define AS_LOCAL(p)  ((__attribute__((address_space(3))) void*)(p))

__device__ __forceinline__ float b2f(unsigned short u) {
    union { unsigned int u; float f; } c; c.u = ((unsigned int)u) << 16; return c.f;
}
__device__ __forceinline__ unsigned short f2b(float f) {
    union { float f; unsigned int u; } c; c.f = f;
    unsigned int u = c.u;
    unsigned int r = (u + 0x7fffu + ((u >> 16) & 1u)) >> 16;
    return (unsigned short)r;
}
__device__ __forceinline__ unsigned char f2fp8(float v) {
    return (unsigned char)(__builtin_amdgcn_cvt_pk_fp8_f32(v, v, 0, false) & 0xff);
}

// ---------------- cast x: fp32 -> bf16 AND fp8(e4m3) in one pass ----------------
__global__ __launch_bounds__(256) void cast_x(
    const float* __restrict__ in, unsigned short* __restrict__ xbf,
    unsigned int* __restrict__ xf8, int n4) {
    int i = blockIdx.x * 256 + threadIdx.x;
    if (i >= n4) return;
    float4 v = ((const float4*)in)[i];
    ushort4 o;
    o.x = f2b(v.x); o.y = f2b(v.y); o.z = f2b(v.z); o.w = f2b(v.w);
    ((ushort4*)xbf)[i] = o;
    int p = __builtin_amdgcn_cvt_pk_fp8_f32(v.x, v.y, 0, false);
    p = __builtin_amdgcn_cvt_pk_fp8_f32(v.z, v.w, p, true);
    xf8[i] = (unsigned int)p;
}

// ---------------- transpose fp32 [R][C] -> bf16 [C][R] (weights, small) ----------------
__global__ __launch_bounds__(256) void transpose_f32_bf16(
    const float* __restrict__ in, unsigned short* __restrict__ out, int R, int C) {
    __shared__ float t[32][33];
    int c0 = blockIdx.x * 32, r0 = blockIdx.y * 32;
    int tx = threadIdx.x, ty = threadIdx.y;
#pragma unroll
    for (int k = 0; k < 32; k += 8)
        t[ty + k][tx] = in[(size_t)(r0 + ty + k) * C + c0 + tx];
    __syncthreads();
#pragma unroll
    for (int k = 0; k < 32; k += 8)
        out[(size_t)(c0 + ty + k) * R + r0 + tx] = f2b(t[tx][ty + k]);
}

// ---------------- transpose Wqkv[:, :2048] fp32 [1024][3072] -> fp8 [2048][1024] ----------------
__global__ __launch_bounds__(256) void transpose_f32_fp8_qk(
    const float* __restrict__ in, unsigned char* __restrict__ out) {
    __shared__ float t[32][33];
    int c0 = blockIdx.x * 32, r0 = blockIdx.y * 32;   // c: 0..2048, r: 0..1024
    int tx = threadIdx.x, ty = threadIdx.y;
#pragma unroll
    for (int k = 0; k < 32; k += 8)
        t[ty + k][tx] = in[(size_t)(r0 + ty + k) * 3072 + c0 + tx];
    __syncthreads();
#pragma unroll
    for (int k = 0; k < 32; k += 8)
        out[(size_t)(c0 + ty + k) * 1024 + r0 + tx] = f2fp8(t[tx][ty + k]);
}

// ---------------- Wv slice: fp32 Wqkv[:,2048:3072] -> bf16 [1024][1024] ----------------
__global__ __launch_bounds__(256) void cast_wv(
    const float* __restrict__ in, unsigned short* __restrict__ out) {
    int i = blockIdx.x * 256 + threadIdx.x;   // over 262144 float4s
    int d = i >> 8, rem = (i & 255) * 4;
    float4 v = *(const float4*)&in[(size_t)d * 3072 + 2048 + rem];
    ushort4 o;
    o.x = f2b(v.x); o.y = f2b(v.y); o.z = f2b(v.z); o.w = f2b(v.w);
    *(ushort4*)&out[(size_t)d * 1024 + rem] = o;
}

// ---------------- bvo[e] = sum_h bqkv[2048+h]*WoT[e][h] + bout[e] ----------------
__global__ __launch_bounds__(256) void bvo_kernel(
    const unsigned short* __restrict__ WoT, const float* __restrict__ bqkv,
    const float* __restrict__ bout, float* __restrict__ bvo) {
    int wv = threadIdx.x >> 6, lane = threadIdx.x & 63;
    int e = blockIdx.x * 4 + wv;
    const unsigned short* row = WoT + (size_t)e * 1024;
    float s = 0.f;
    for (int h = lane; h < 1024; h += 64) s += b2f(row[h]) * bqkv[2048 + h];
#pragma unroll
    for (int o = 32; o; o >>= 1) s += __shfl_xor(s, o);
    if (lane == 0) bvo[e] = s + bout[e];
}

// ---------------- double softmax + mask, in place on S (bf16) ----------------
__global__ __launch_bounds__(256) void softmax2_kernel(
    unsigned short* __restrict__ S, const int* __restrict__ mask) {
    const int N = 2048;
    int wv = threadIdx.x >> 6, lane = threadIdx.x & 63;
    size_t row = (size_t)blockIdx.x * 4 + wv;
    unsigned short* srow = S + row * N;
    const int* mrow = mask + row * N;

    float e1[32];
    float l = 0.f;
#pragma unroll
    for (int i = 0; i < 4; ++i) {
        uint4 raw = ((const uint4*)srow)[lane + 64 * i];
        unsigned v[4] = { raw.x, raw.y, raw.z, raw.w };
#pragma unroll
        for (int j = 0; j < 4; ++j) {
            float a = b2f((unsigned short)(v[j] & 0xffff));
            float bb = b2f((unsigned short)(v[j] >> 16));
            float ea = __expf(a), eb = __expf(bb);
            e1[i * 8 + 2 * j] = ea; e1[i * 8 + 2 * j + 1] = eb;
            l += ea + eb;
        }
    }
#pragma unroll
    for (int o = 32; o; o >>= 1) l += __shfl_xor(l, o);
    float invl = 1.0f / l;

    float e2[32];
    float z = 0.f;
#pragma unroll
    for (int i = 0; i < 4; ++i) {
        uint4 m0 = ((const uint4*)mrow)[2 * (lane + 64 * i)];
        uint4 m1 = ((const uint4*)mrow)[2 * (lane + 64 * i) + 1];
        int mk[8] = { (int)m0.x, (int)m0.y, (int)m0.z, (int)m0.w,
                      (int)m1.x, (int)m1.y, (int)m1.z, (int)m1.w };
#pragma unroll
        for (int j = 0; j < 8; ++j) {
            float w1 = e1[i * 8 + j] * invl;
            float e = mk[j] ? __expf(w1) : 0.0f;
            e2[i * 8 + j] = e; z += e;
        }
    }
#pragma unroll
    for (int o = 32; o; o >>= 1) z += __shfl_xor(z, o);
    float invz = (z > 0.f) ? 1.0f / z : 0.0f;
    float fallback = 1.0f / N;
#pragma unroll
    for (int i = 0; i < 4; ++i) {
        float p[8];
#pragma unroll
        for (int j = 0; j < 8; ++j)
            p[j] = (z > 0.f) ? e2[i * 8 + j] * invz : fallback;
        uint4 o;
        o.x = (unsigned)f2b(p[0]) | ((unsigned)f2b(p[1]) << 16);
        o.y = (unsigned)f2b(p[2]) | ((unsigned)f2b(p[3]) << 16);
        o.z = (unsigned)f2b(p[4]) | ((unsigned)f2b(p[5]) << 16);
        o.w = (unsigned)f2b(p[6]) | ((unsigned)f2b(p[7]) << 16);
        ((uint4*)srow)[lane + 64 * i] = o;
    }
}

// ---------------- bf16 GEMM, B in [n][k] layout, m97-style ----------------
// OUT: 0 = bf16 C[m][n], 1 = f32 C[m][n], 2 = bf16 transposed VpT-write:
//      C[batch][n][m] with batch = tm0>>11 (M is flattened tokens, 2048/batch).
template <int TAG, bool BIAS, int OUT, int XS, int YS>
__global__ __launch_bounds__(256) void gemm_bt(
    const unsigned short* __restrict__ A, int ldA, long long strideA,
    const unsigned short* __restrict__ B, int ldB, long long strideB,
    void* __restrict__ C, int ldC, long long strideC,
    const float* __restrict__ bias, float scale, int K) {
    __shared__ __align__(16) unsigned short lds[2 * 128 * 64];
    unsigned short* At = lds;
    unsigned short* Bt = lds + 128 * 64;

    // XCD swizzle: nwg % 8 == 0 for all launches (bijective chunked remap)
    unsigned flat = blockIdx.x;
    unsigned wg = (flat & 7u) * (gridDim.x >> 3) + (flat >> 3);
    int bx = wg & ((1u << XS) - 1u);
    int by = (wg >> XS) & ((1u << YS) - 1u);
    int bz = wg >> (XS + YS);

    const unsigned short* Ab = A + (size_t)bz * strideA;
    const unsigned short* Bb = B + (size_t)bz * strideB;
    int tn0 = bx * 128;
    int tm0 = by * 128;
    int tid = threadIdx.x;
    int wave = tid >> 6, lane = tid & 63;
    int lm = lane & 15, q = lane >> 4;
    int wm = (wave >> 1) * 64, wn = (wave & 1) * 64;

    int srow = lane >> 3;
    int sblk = lane & 7;

    floatx4 acc[4][4] = {};

    for (int k0 = 0; k0 < K; k0 += 64) {
        __syncthreads();
#pragma unroll
        for (int i = 0; i < 4; ++i) {
            int chunk = wave * 4 + i;
            int r = chunk * 8 + srow;
            int blk = sblk ^ (r & 7);
            const unsigned short* ga = Ab + (size_t)(tm0 + r) * ldA + (k0 + blk * 8);
            __builtin_amdgcn_global_load_lds(AS_GLOBAL(ga), AS_LOCAL(At + chunk * 512), 16, 0, 0);
            const unsigned short* gb = Bb + (size_t)(tn0 + r) * ldB + (k0 + blk * 8);
            __builtin_amdgcn_global_load_lds(AS_GLOBAL(gb), AS_LOCAL(Bt + chunk * 512), 16, 0, 0);
        }
        __syncthreads();
#pragma unroll
        for (int kk = 0; kk < 2; ++kk) {
            short8 af[4], bf[4];
#pragma unroll
            for (int mt = 0; mt < 4; ++mt) {
                int r = wm + mt * 16 + lm;
                af[mt] = *(const short8*)(At + r * 64 + (((kk * 4 + q) ^ (r & 7)) * 8));
            }
#pragma unroll
            for (int nt = 0; nt < 4; ++nt) {
                int r = wn + nt * 16 + lm;
                bf[nt] = *(const short8*)(Bt + r * 64 + (((kk * 4 + q) ^ (r & 7)) * 8));
            }
#pragma unroll
            for (int mt = 0; mt < 4; ++mt)
#pragma unroll
                for (int nt = 0; nt < 4; ++nt)
                    acc[mt][nt] = __builtin_amdgcn_mfma_f32_16x16x32_bf16(
                        af[mt], bf[nt], acc[mt][nt], 0, 0, 0);
        }
    }

    float biasv[4];
#pragma unroll
    for (int nt = 0; nt < 4; ++nt)
        biasv[nt] = BIAS ? bias[tn0 + wn + nt * 16 + lm] : 0.0f;

    if (OUT == 2) {
        __syncthreads();
        unsigned short* T = lds;   // [128][128] bf16, col = m ^ ((n&15)<<3)
#pragma unroll
        for (int mt = 0; mt < 4; ++mt)
#pragma unroll
            for (int nt = 0; nt < 4; ++nt) {
                int n = wn + nt * 16 + lm;
                int m0 = wm + mt * 16 + q * 4;
                int col = m0 ^ ((n & 15) << 3);
                ushort4 pv;
                float v0 = acc[mt][nt][0] * scale; if (BIAS) v0 += biasv[nt];
                float v1 = acc[mt][nt][1] * scale; if (BIAS) v1 += biasv[nt];
                float v2 = acc[mt][nt][2] * scale; if (BIAS) v2 += biasv[nt];
                float v3 = acc[mt][nt][3] * scale; if (BIAS) v3 += biasv[nt];
                pv.x = f2b(v0); pv.y = f2b(v1); pv.z = f2b(v2); pv.w = f2b(v3);
                *(ushort4*)&T[n * 128 + col] = pv;
            }
        __syncthreads();
        unsigned short* Cb = (unsigned short*)C + (size_t)(tm0 >> 11) * strideC + (tm0 & 2047);
#pragma unroll
        for (int r8 = 0; r8 < 8; ++r8) {
            int idx = tid + 256 * r8;        // 0..2047 over 128 rows x 16 chunks
            int d = idx >> 4, c = idx & 15;
            int cs = (c ^ (d & 15)) << 3;    // inverse of the write swizzle
            short8 v = *(const short8*)&T[d * 128 + cs];
            *(short8*)&Cb[(size_t)(tn0 + d) * ldC + c * 8] = v;
        }
        return;
    }

#pragma unroll
    for (int mt = 0; mt < 4; ++mt) {
#pragma unroll
        for (int nt = 0; nt < 4; ++nt) {
            int gm = tm0 + wm + mt * 16 + q * 4;
            int gn = tn0 + wn + nt * 16 + lm;
#pragma unroll
            for (int r = 0; r < 4; ++r) {
                float v = acc[mt][nt][r] * scale;
                if (BIAS) v += biasv[nt];
                size_t idx = (size_t)bz * strideC + (size_t)(gm + r) * ldC + gn;
                if (OUT == 1) ((float*)C)[idx] = v;
                else          ((unsigned short*)C)[idx] = f2b(v);
            }
        }
    }
}

// ---------------- bf16 256x256 8-phase GEMM (T3+T4+T5), hardened ----------------
// 512 threads = 8 waves (2M x 4N), per-wave 128x64, BK=64, 128 KB LDS.
// LAYOUT CONSTANTS: one tile = 256 rows x 64 cols bf16 = 16384 elements (32 KB).
//   A buffers: lds + {0, 16384}; B buffers: lds + 32768 + {0, 16384}.  (r3 bug
//   was stride 8192 = half a tile -> stage overlapped read buffer.)
// SAFETY INVARIANTS:
//  * disjoint double-buffer: tile t+1 stages into buf[(t+1)&1], never the read buf.
//  * single drain point: vmcnt(0) + s_barrier at iteration end, before swap.
//    B(t+1) issues in phase 1, A(t+1) in phase 2 -> ~3 MFMA phases of latency
//    cover before the drain.
//  * per-phase barriers are only for the T3 lockstep schedule; all branches
//    uniform -> uniform barrier counts.
template <int MH>
__device__ __forceinline__ void mfma16(floatx4 (&acc)[8][4], const short8 (&af)[4],
                                       const short8 (&bf)[4]) {
#pragma unroll
    for (int m = 0; m < 4; ++m)
#pragma unroll
        for (int n = 0; n < 4; ++n)
            acc[MH * 4 + m][n] = __builtin_amdgcn_mfma_f32_16x16x32_bf16(
                af[m], bf[n], acc[MH * 4 + m][n], 0, 0, 0);
}

template <int NXB, int NYB>
__global__ __launch_bounds__(512, 2) void gemm_bt8(
    const unsigned short* __restrict__ A, int ldA, long long strideA,
    const unsigned short* __restrict__ B, int ldB, long long strideB,
    float* __restrict__ C, int ldC, long long strideC,
    float scale, int K) {
    __shared__ __align__(16) unsigned short lds[65536];   // A:2x32KB | B:2x32KB
    constexpr int TILE = 16384;                           // elements per tile buffer
    constexpr int BREG = 32768;                           // B region element offset

    int tid = threadIdx.x;
    int wave = tid >> 6, lane = tid & 63;
    int lm = lane & 15, q = lane >> 4;
    int wmi = wave >> 2, wni = wave & 3;

    unsigned flat = blockIdx.x;
    unsigned wg = (flat & 7u) * (gridDim.x >> 3) + (flat >> 3);
    int bx = wg % NXB;
    int rem = wg / NXB;
    int by = rem % NYB;
    int bz = rem / NYB;
    int tn0 = bx * 256, tm0 = by * 256;

    const unsigned short* Ab = A + (size_t)bz * strideA;
    const unsigned short* Bb = B + (size_t)bz * strideB;

    // staging: load i covers rows [i*64+wave*8 .. +8); slot = lane&7 holds global
    // k-chunk slot^(row&7) (proven m97 XOR swizzle; 0 bank conflicts measured)
    int srow8 = lane >> 3, s7 = lane & 7;
    const unsigned short* gA[4];
    const unsigned short* gB[4];
#pragma unroll
    for (int i = 0; i < 4; ++i) {
        int r = i * 64 + wave * 8 + srow8;
        int blk = s7 ^ (r & 7);
        gA[i] = Ab + (size_t)(tm0 + r) * ldA + blk * 8;
        gB[i] = Bb + (size_t)(tn0 + r) * ldB + blk * 8;
    }

    int nt = K >> 6;

    // prologue: stage tile 0 into buffer 0, full drain
#pragma unroll
    for (int i = 0; i < 4; ++i)
        __builtin_amdgcn_global_load_lds(AS_GLOBAL(gB[i]), AS_LOCAL(lds + BREG + i * 4096 + wave * 512), 16, 0, 0);
#pragma unroll
    for (int i = 0; i < 4; ++i)
        __builtin_amdgcn_global_load_lds(AS_GLOBAL(gA[i]), AS_LOCAL(lds + i * 4096 + wave * 512), 16, 0, 0);
#pragma unroll
    for (int i = 0; i < 4; ++i) { gA[i] += 64; gB[i] += 64; }   // -> tile 1

    asm volatile("s_waitcnt vmcnt(0)" ::: "memory");
    __builtin_amdgcn_s_barrier();

    floatx4 acc[8][4] = {};
    short8 bf0[4], bf1[4];
    short8 af[4];

    int aOff = (wmi * 128 + lm) * 64;       // element offset of this wave's A rows
    int bOff = (wni * 64 + lm) * 64;        // element offset of this wave's B rows
    int sl0 = (q ^ (lm & 7)) * 8;           // kk=0 chunk slot
    int sl1 = ((4 + q) ^ (lm & 7)) * 8;     // kk=1 chunk slot

    for (int t = 0; t < nt; ++t) {
        unsigned short* Ap = lds + (t & 1) * TILE;               // read buffers
        unsigned short* Bp = lds + BREG + (t & 1) * TILE;
        unsigned short* An = lds + ((t + 1) & 1) * TILE;         // stage buffers
        unsigned short* Bn = lds + BREG + ((t + 1) & 1) * TILE;
        bool pre = (t + 1) < nt;

        // ---- phase 1: all 8 B frags + A(mh0,kk0); issue B(t+1) ----
#pragma unroll
        for (int n = 0; n < 4; ++n) bf0[n] = *(const short8*)(Bp + bOff + n * 1024 + sl0);
#pragma unroll
        for (int n = 0; n < 4; ++n) bf1[n] = *(const short8*)(Bp + bOff + n * 1024 + sl1);
#pragma unroll
        for (int m = 0; m < 4; ++m) af[m] = *(const short8*)(Ap + aOff + m * 1024 + sl0);
        if (pre) {
#pragma unroll
            for (int i = 0; i < 4; ++i)
                __builtin_amdgcn_global_load_lds(AS_GLOBAL(gB[i]), AS_LOCAL(Bn + i * 4096 + wave * 512), 16, 0, 0);
        }
        __builtin_amdgcn_sched_barrier(0);
        __builtin_amdgcn_s_barrier();
        asm volatile("s_waitcnt lgkmcnt(0)" ::: "memory");
        __builtin_amdgcn_sched_barrier(0);
        __builtin_amdgcn_s_setprio(1);
        mfma16<0>(acc, af, bf0);
        __builtin_amdgcn_s_setprio(0);
        __builtin_amdgcn_s_barrier();

        // ---- phase 2: A(mh1,kk0); issue A(t+1) ----
#pragma unroll
        for (int m = 0; m < 4; ++m) af[m] = *(const short8*)(Ap + aOff + 4096 + m * 1024 + sl0);
        if (pre) {
#pragma unroll
            for (int i = 0; i < 4; ++i)
                __builtin_amdgcn_global_load_lds(AS_GLOBAL(gA[i]), AS_LOCAL(An + i * 4096 + wave * 512), 16, 0, 0);
#pragma unroll
            for (int i = 0; i < 4; ++i) { gA[i] += 64; gB[i] += 64; }
        }
        __builtin_amdgcn_sched_barrier(0);
        __builtin_amdgcn_s_barrier();
        asm volatile("s_waitcnt lgkmcnt(0)" ::: "memory");
        __builtin_amdgcn_sched_barrier(0);
        __builtin_amdgcn_s_setprio(1);
        mfma16<1>(acc, af, bf0);
        __builtin_amdgcn_s_setprio(0);
        __builtin_amdgcn_s_barrier();

        // ---- phase 3: A(mh0,kk1) ----
#pragma unroll
        for (int m = 0; m < 4; ++m) af[m] = *(const short8*)(Ap + aOff + m * 1024 + sl1);
        __builtin_amdgcn_sched_barrier(0);
        __builtin_amdgcn_s_barrier();
        asm volatile("s_waitcnt lgkmcnt(0)" ::: "memory");
        __builtin_amdgcn_sched_barrier(0);
        __builtin_amdgcn_s_setprio(1);
        mfma16<0>(acc, af, bf1);
        __builtin_amdgcn_s_setprio(0);
        __builtin_amdgcn_s_barrier();

        // ---- phase 4: A(mh1,kk1); drain staging, swap ----
#pragma unroll
        for (int m = 0; m < 4; ++m) af[m] = *(const short8*)(Ap + aOff + 4096 + m * 1024 + sl1);
        __builtin_amdgcn_sched_barrier(0);
        __builtin_amdgcn_s_barrier();
        asm volatile("s_waitcnt lgkmcnt(0)" ::: "memory");
        __builtin_amdgcn_sched_barrier(0);
        __builtin_amdgcn_s_setprio(1);
        mfma16<1>(acc, af, bf1);
        __builtin_amdgcn_s_setprio(0);
        asm volatile("s_waitcnt vmcnt(0)" ::: "memory");
        __builtin_amdgcn_s_barrier();
    }

    float* Cb = C + (size_t)bz * strideC;
#pragma unroll
    for (int m = 0; m < 8; ++m) {
#pragma unroll
        for (int n = 0; n < 4; ++n) {
            int gm = tm0 + wmi * 128 + m * 16 + q * 4;
            int gn = tn0 + wni * 64 + n * 16 + lm;
#pragma unroll
            for (int r = 0; r < 4; ++r)
                Cb[(size_t)(gm + r) * ldC + gn] = acc[m][n][r] * scale;
        }
    }
}

// ---------------- fp8(e4m3) GEMM via mfma_scale 16x16x128, unit scales ----------------
template <int TAG, bool BIAS, bool OUTFP8, int XS, int YS>
__global__ __launch_bounds__(256) void gemm_f8_bt(
    const unsigned char* __restrict__ A, int ldA, long long strideA,
    const unsigned char* __restrict__ B, int ldB, long long strideB,
    void* __restrict__ C, int ldC, long long strideC,
    const float* __restrict__ bias, float scale, int K) {
    __shared__ __align__(16) unsigned char lds[2 * 128 * 128];
    unsigned char* At = lds;
    unsigned char* Bt = lds + 128 * 128;

    unsigned flat = blockIdx.x;
    unsigned wg = (flat & 7u) * (gridDim.x >> 3) + (flat >> 3);
    int bx = wg & ((1u << XS) - 1u);
    int by = (wg >> XS) & ((1u << YS) - 1u);
    int bz = wg >> (XS + YS);

    const unsigned char* Ab = A + (size_t)bz * strideA;
    const unsigned char* Bb = B + (size_t)bz * strideB;
    int tn0 = bx * 128;
    int tm0 = by * 128;
    int tid = threadIdx.x;
    int wave = tid >> 6, lane = tid & 63;
    int lm = lane & 15, q = lane >> 4;
    int q2 = q * 2;
    int wm = (wave >> 1) * 64, wn = (wave & 1) * 64;

    int srow = lane >> 3;
    int sblk = lane & 7;

    floatx4 acc[4][4] = {};

    for (int k0 = 0; k0 < K; k0 += 128) {
        __syncthreads();
#pragma unroll
        for (int i = 0; i < 4; ++i) {
            int chunk = wave * 4 + i;
            int r = chunk * 8 + srow;
            int blk = sblk ^ (r & 7);
            const unsigned char* ga = Ab + (size_t)(tm0 + r) * ldA + (k0 + blk * 16);
            __builtin_amdgcn_global_load_lds(AS_GLOBAL(ga), AS_LOCAL(At + chunk * 1024), 16, 0, 0);
            const unsigned char* gb = Bb + (size_t)(tn0 + r) * ldB + (k0 + blk * 16);
            __builtin_amdgcn_global_load_lds(AS_GLOBAL(gb), AS_LOCAL(Bt + chunk * 1024), 16, 0, 0);
        }
        __syncthreads();
        intx8 af[4], bf[4];
#pragma unroll
        for (int mt = 0; mt < 4; ++mt) {
            int r = wm + mt * 16 + lm;
            const unsigned char* base = At + r * 128;
            int4 lo = *(const int4*)(base + ((q2 ^ (r & 7)) << 4));
            int4 hi = *(const int4*)(base + (((q2 + 1) ^ (r & 7)) << 4));
            af[mt][0] = lo.x; af[mt][1] = lo.y; af[mt][2] = lo.z; af[mt][3] = lo.w;
            af[mt][4] = hi.x; af[mt][5] = hi.y; af[mt][6] = hi.z; af[mt][7] = hi.w;
        }
#pragma unroll
        for (int nt = 0; nt < 4; ++nt) {
            int r = wn + nt * 16 + lm;
            const unsigned char* base = Bt + r * 128;
            int4 lo = *(const int4*)(base + ((q2 ^ (r & 7)) << 4));
            int4 hi = *(const int4*)(base + (((q2 + 1) ^ (r & 7)) << 4));
            bf[nt][0] = lo.x; bf[nt][1] = lo.y; bf[nt][2] = lo.z; bf[nt][3] = lo.w;
            bf[nt][4] = hi.x; bf[nt][5] = hi.y; bf[nt][6] = hi.z; bf[nt][7] = hi.w;
        }
#pragma unroll
        for (int mt = 0; mt < 4; ++mt)
#pragma unroll
            for (int nt = 0; nt < 4; ++nt)
                acc[mt][nt] = __builtin_amdgcn_mfma_scale_f32_16x16x128_f8f6f4(
                    af[mt], bf[nt], acc[mt][nt], 0, 0,
                    0, 0x7f7f7f7f, 0, 0x7f7f7f7f);
    }

    float biasv[4];
#pragma unroll
    for (int nt = 0; nt < 4; ++nt)
        biasv[nt] = BIAS ? bias[tn0 + wn + nt * 16 + lm] : 0.0f;
#pragma unroll
    for (int mt = 0; mt < 4; ++mt) {
#pragma unroll
        for (int nt = 0; nt < 4; ++nt) {
            int gm = tm0 + wm + mt * 16 + q * 4;
            int gn = tn0 + wn + nt * 16 + lm;
#pragma unroll
            for (int r = 0; r < 4; ++r) {
                float v = acc[mt][nt][r] * scale;
                if (BIAS) v += biasv[nt];
                size_t idx = (size_t)bz * strideC + (size_t)(gm + r) * ldC + gn;
                if (OUTFP8) ((unsigned char*)C)[idx] = f2fp8(v);
                else        ((unsigned short*)C)[idx] = f2b(v);
            }
        }
    }
}

extern "C" void kernel_launch(void* const* d_in, const int* in_sizes, int n_in,
                              void* d_out, int out_size, void* d_ws, size_t ws_size,
                              hipStream_t stream) {
    const float* x    = (const float*)d_in[0];   // [8,2048,1024]
    const int*   mask = (const int*)d_in[1];     // [8,2048,2048]
    const float* Wqkv = (const float*)d_in[2];   // [1024,3072]
    const float* bqkv = (const float*)d_in[3];   // [3072]
    const float* Wout = (const float*)d_in[4];   // [1024,1024]
    const float* bout = (const float*)d_in[5];   // [1024]
    float* out = (float*)d_out;                  // [8,2048,1024]

    char* w = (char*)d_ws;
    unsigned short* x_bf  = (unsigned short*)(w);              // 33,554,432
    unsigned char*  x_f8  = (unsigned char*)(w + 33554432);    // 16,777,216
    unsigned char*  QKf8  = (unsigned char*)(w + 50331648);    // 33,554,432  [16384][2048]: Q cols 0..1023, K cols 1024..2047
    unsigned short* VpT   = (unsigned short*)(w + 117440512);  // 33,554,432  [8][1024][2048]
    unsigned short* S     = (unsigned short*)(w + 150994944);  // 67,108,864
    unsigned char*  WqkT8 = (unsigned char*)(w + 218103808);   //  2,097,152
    unsigned short* WoT   = (unsigned short*)(w + 220200960);  //  2,097,152
    unsigned short* Wv_bf = (unsigned short*)(w + 222298112);  //  2,097,152
    unsigned short* WvoT  = (unsigned short*)(w + 224395264);  //  2,097,152
    float*          bvo   = (float*)(w + 226492416);           //      4,096  -> 226.5 MB total

    // 1) input casts / weight prep
    cast_x<<<16384, 256, 0, stream>>>(x, x_bf, (unsigned int*)x_f8, 4194304);
    transpose_f32_fp8_qk<<<dim3(64, 32), dim3(32, 8), 0, stream>>>(Wqkv, WqkT8);
    transpose_f32_bf16<<<dim3(32, 32), dim3(32, 8), 0, stream>>>(Wout, WoT, 1024, 1024);
    cast_wv<<<1024, 256, 0, stream>>>(Wqkv, Wv_bf);
    bvo_kernel<<<256, 256, 0, stream>>>(WoT, bqkv, bout, bvo);

    // 2) WvoT = (Wv @ Wout)^T : C[e][d] = sum_h WoT[e][h] * Wv[d][h]   (grid 8x8 -> 64)
    gemm_bt<4, false, 0, 3, 3><<<64, 256, 0, stream>>>(
        WoT, 1024, 0, Wv_bf, 1024, 0, WvoT, 1024, 0, nullptr, 1.0f, 1024);

    // 3) QK projection in fp8: [16384][2048] = x_f8 @ WqkT8^T + bqkv[0:2048]
    gemm_f8_bt<0, true, true, 4, 7><<<2048, 256, 0, stream>>>(
        x_f8, 1024, 0, WqkT8, 1024, 0, QKf8, 2048, 0, bqkv, 1.0f, 1024);

    // 4) V'^T = (x @ Wvo + bvo)^T, transposed epilogue writes VpT [8][1024][2048] directly
    gemm_bt<5, true, 2, 3, 7><<<1024, 256, 0, stream>>>(
        x_bf, 1024, 0, WvoT, 1024, 0, VpT, 2048, 1024LL * 2048, bvo, 1.0f, 1024);

    // 5) S = Q @ K^T / sqrt(D) in fp8 -> bf16 [8][2048][2048]
    gemm_f8_bt<1, false, false, 4, 4><<<2048, 256, 0, stream>>>(
        QKf8, 2048, 2048LL * 2048, QKf8 + 1024, 2048, 2048LL * 2048,
        S, 2048, 2048LL * 2048, nullptr, 0.03125f, 1024);

    // 6) softmax -> mask -> softmax, in place
    softmax2_kernel<<<4096, 256, 0, stream>>>(S, mask);

    // 7) out = P @ V' -> fp32 d_out, 256^2 8-phase kernel
    //    grid 4x8x8 = 256 blocks = 1/CU; XCD k <-> batch k
    gemm_bt8<4, 8><<<256, 512, 0, stream>>>(
        S, 2048, 2048LL * 2048, VpT, 2048, 1024LL * 2048,
        out, 1024, 2048LL * 1024, 1.0f, 2048);
}

// Round 5
// 499.323 us; speedup vs baseline: 1.1385x; 1.0019x over previous
//
#include <hip/hip_runtime.h>
#include <hip/hip_bf16.h>

typedef __attribute__((ext_vector_type(8))) short short8;
typedef __attribute__((ext_vector_type(4))) float floatx4;
typedef __attribute__((ext_vector_type(8))) int intx8;

#define AS_GLOBAL(p) ((const __attribute__((address_space(1))) void*)(p))
#define AS_LOCAL(p)  ((__attribute__((address_space(3))) void*)(p))

__device__ __forceinline__ float b2f(unsigned short u) {
    union { unsigned int u; float f; } c; c.u = ((unsigned int)u) << 16; return c.f;
}
__device__ __forceinline__ unsigned short f2b(float f) {
    union { float f; unsigned int u; } c; c.f = f;
    unsigned int u = c.u;
    unsigned int r = (u + 0x7fffu + ((u >> 16) & 1u)) >> 16;
    return (unsigned short)r;
}
__device__ __forceinline__ unsigned char f2fp8(float v) {
    return (unsigned char)(__builtin_amdgcn_cvt_pk_fp8_f32(v, v, 0, false) & 0xff);
}

// ---------------- cast x: fp32 -> bf16 AND fp8(e4m3) in one pass ----------------
__global__ __launch_bounds__(256) void cast_x(
    const float* __restrict__ in, unsigned short* __restrict__ xbf,
    unsigned int* __restrict__ xf8, int n4) {
    int i = blockIdx.x * 256 + threadIdx.x;
    if (i >= n4) return;
    float4 v = ((const float4*)in)[i];
    ushort4 o;
    o.x = f2b(v.x); o.y = f2b(v.y); o.z = f2b(v.z); o.w = f2b(v.w);
    ((ushort4*)xbf)[i] = o;
    int p = __builtin_amdgcn_cvt_pk_fp8_f32(v.x, v.y, 0, false);
    p = __builtin_amdgcn_cvt_pk_fp8_f32(v.z, v.w, p, true);
    xf8[i] = (unsigned int)p;
}

// ---------------- transpose fp32 [R][C] -> bf16 [C][R] (weights, small) ----------------
__global__ __launch_bounds__(256) void transpose_f32_bf16(
    const float* __restrict__ in, unsigned short* __restrict__ out, int R, int C) {
    __shared__ float t[32][33];
    int c0 = blockIdx.x * 32, r0 = blockIdx.y * 32;
    int tx = threadIdx.x, ty = threadIdx.y;
#pragma unroll
    for (int k = 0; k < 32; k += 8)
        t[ty + k][tx] = in[(size_t)(r0 + ty + k) * C + c0 + tx];
    __syncthreads();
#pragma unroll
    for (int k = 0; k < 32; k += 8)
        out[(size_t)(c0 + ty + k) * R + r0 + tx] = f2b(t[tx][ty + k]);
}

// ---------------- transpose Wqkv[:, :2048] fp32 [1024][3072] -> fp8 [2048][1024] ----------------
__global__ __launch_bounds__(256) void transpose_f32_fp8_qk(
    const float* __restrict__ in, unsigned char* __restrict__ out) {
    __shared__ float t[32][33];
    int c0 = blockIdx.x * 32, r0 = blockIdx.y * 32;   // c: 0..2048, r: 0..1024
    int tx = threadIdx.x, ty = threadIdx.y;
#pragma unroll
    for (int k = 0; k < 32; k += 8)
        t[ty + k][tx] = in[(size_t)(r0 + ty + k) * 3072 + c0 + tx];
    __syncthreads();
#pragma unroll
    for (int k = 0; k < 32; k += 8)
        out[(size_t)(c0 + ty + k) * 1024 + r0 + tx] = f2fp8(t[tx][ty + k]);
}

// ---------------- Wv slice: fp32 Wqkv[:,2048:3072] -> bf16 [1024][1024] ----------------
__global__ __launch_bounds__(256) void cast_wv(
    const float* __restrict__ in, unsigned short* __restrict__ out) {
    int i = blockIdx.x * 256 + threadIdx.x;   // over 262144 float4s
    int d = i >> 8, rem = (i & 255) * 4;
    float4 v = *(const float4*)&in[(size_t)d * 3072 + 2048 + rem];
    ushort4 o;
    o.x = f2b(v.x); o.y = f2b(v.y); o.z = f2b(v.z); o.w = f2b(v.w);
    *(ushort4*)&out[(size_t)d * 1024 + rem] = o;
}

// ---------------- bvo[e] = sum_h bqkv[2048+h]*WoT[e][h] + bout[e] ----------------
__global__ __launch_bounds__(256) void bvo_kernel(
    const unsigned short* __restrict__ WoT, const float* __restrict__ bqkv,
    const float* __restrict__ bout, float* __restrict__ bvo) {
    int wv = threadIdx.x >> 6, lane = threadIdx.x & 63;
    int e = blockIdx.x * 4 + wv;
    const unsigned short* row = WoT + (size_t)e * 1024;
    float s = 0.f;
    for (int h = lane; h < 1024; h += 64) s += b2f(row[h]) * bqkv[2048 + h];
#pragma unroll
    for (int o = 32; o; o >>= 1) s += __shfl_xor(s, o);
    if (lane == 0) bvo[e] = s + bout[e];
}

// ---------------- double softmax + mask, in place on S (bf16) ----------------
__global__ __launch_bounds__(256) void softmax2_kernel(
    unsigned short* __restrict__ S, const int* __restrict__ mask) {
    const int N = 2048;
    int wv = threadIdx.x >> 6, lane = threadIdx.x & 63;
    size_t row = (size_t)blockIdx.x * 4 + wv;
    unsigned short* srow = S + row * N;
    const int* mrow = mask + row * N;

    float e1[32];
    float l = 0.f;
#pragma unroll
    for (int i = 0; i < 4; ++i) {
        uint4 raw = ((const uint4*)srow)[lane + 64 * i];
        unsigned v[4] = { raw.x, raw.y, raw.z, raw.w };
#pragma unroll
        for (int j = 0; j < 4; ++j) {
            float a = b2f((unsigned short)(v[j] & 0xffff));
            float bb = b2f((unsigned short)(v[j] >> 16));
            float ea = __expf(a), eb = __expf(bb);
            e1[i * 8 + 2 * j] = ea; e1[i * 8 + 2 * j + 1] = eb;
            l += ea + eb;
        }
    }
#pragma unroll
    for (int o = 32; o; o >>= 1) l += __shfl_xor(l, o);
    float invl = 1.0f / l;

    float e2[32];
    float z = 0.f;
#pragma unroll
    for (int i = 0; i < 4; ++i) {
        uint4 m0 = ((const uint4*)mrow)[2 * (lane + 64 * i)];
        uint4 m1 = ((const uint4*)mrow)[2 * (lane + 64 * i) + 1];
        int mk[8] = { (int)m0.x, (int)m0.y, (int)m0.z, (int)m0.w,
                      (int)m1.x, (int)m1.y, (int)m1.z, (int)m1.w };
#pragma unroll
        for (int j = 0; j < 8; ++j) {
            float w1 = e1[i * 8 + j] * invl;
            float e = mk[j] ? __expf(w1) : 0.0f;
            e2[i * 8 + j] = e; z += e;
        }
    }
#pragma unroll
    for (int o = 32; o; o >>= 1) z += __shfl_xor(z, o);
    float invz = (z > 0.f) ? 1.0f / z : 0.0f;
    float fallback = 1.0f / N;
#pragma unroll
    for (int i = 0; i < 4; ++i) {
        float p[8];
#pragma unroll
        for (int j = 0; j < 8; ++j)
            p[j] = (z > 0.f) ? e2[i * 8 + j] * invz : fallback;
        uint4 o;
        o.x = (unsigned)f2b(p[0]) | ((unsigned)f2b(p[1]) << 16);
        o.y = (unsigned)f2b(p[2]) | ((unsigned)f2b(p[3]) << 16);
        o.z = (unsigned)f2b(p[4]) | ((unsigned)f2b(p[5]) << 16);
        o.w = (unsigned)f2b(p[6]) | ((unsigned)f2b(p[7]) << 16);
        ((uint4*)srow)[lane + 64 * i] = o;
    }
}

// ---------------- bf16 GEMM, B in [n][k] layout, m97-style ----------------
// OUT: 0 = bf16 C[m][n], 1 = f32 C[m][n], 2 = bf16 transposed VpT-write:
//      C[batch][n][m] with batch = tm0>>11 (M is flattened tokens, 2048/batch).
template <int TAG, bool BIAS, int OUT, int XS, int YS>
__global__ __launch_bounds__(256) void gemm_bt(
    const unsigned short* __restrict__ A, int ldA, long long strideA,
    const unsigned short* __restrict__ B, int ldB, long long strideB,
    void* __restrict__ C, int ldC, long long strideC,
    const float* __restrict__ bias, float scale, int K) {
    __shared__ __align__(16) unsigned short lds[2 * 128 * 64];
    unsigned short* At = lds;
    unsigned short* Bt = lds + 128 * 64;

    // XCD swizzle: nwg % 8 == 0 for all launches (bijective chunked remap)
    unsigned flat = blockIdx.x;
    unsigned wg = (flat & 7u) * (gridDim.x >> 3) + (flat >> 3);
    int bx = wg & ((1u << XS) - 1u);
    int by = (wg >> XS) & ((1u << YS) - 1u);
    int bz = wg >> (XS + YS);

    const unsigned short* Ab = A + (size_t)bz * strideA;
    const unsigned short* Bb = B + (size_t)bz * strideB;
    int tn0 = bx * 128;
    int tm0 = by * 128;
    int tid = threadIdx.x;
    int wave = tid >> 6, lane = tid & 63;
    int lm = lane & 15, q = lane >> 4;
    int wm = (wave >> 1) * 64, wn = (wave & 1) * 64;

    int srow = lane >> 3;
    int sblk = lane & 7;

    floatx4 acc[4][4] = {};

    for (int k0 = 0; k0 < K; k0 += 64) {
        __syncthreads();
#pragma unroll
        for (int i = 0; i < 4; ++i) {
            int chunk = wave * 4 + i;
            int r = chunk * 8 + srow;
            int blk = sblk ^ (r & 7);
            const unsigned short* ga = Ab + (size_t)(tm0 + r) * ldA + (k0 + blk * 8);
            __builtin_amdgcn_global_load_lds(AS_GLOBAL(ga), AS_LOCAL(At + chunk * 512), 16, 0, 0);
            const unsigned short* gb = Bb + (size_t)(tn0 + r) * ldB + (k0 + blk * 8);
            __builtin_amdgcn_global_load_lds(AS_GLOBAL(gb), AS_LOCAL(Bt + chunk * 512), 16, 0, 0);
        }
        __syncthreads();
#pragma unroll
        for (int kk = 0; kk < 2; ++kk) {
            short8 af[4], bf[4];
#pragma unroll
            for (int mt = 0; mt < 4; ++mt) {
                int r = wm + mt * 16 + lm;
                af[mt] = *(const short8*)(At + r * 64 + (((kk * 4 + q) ^ (r & 7)) * 8));
            }
#pragma unroll
            for (int nt = 0; nt < 4; ++nt) {
                int r = wn + nt * 16 + lm;
                bf[nt] = *(const short8*)(Bt + r * 64 + (((kk * 4 + q) ^ (r & 7)) * 8));
            }
#pragma unroll
            for (int mt = 0; mt < 4; ++mt)
#pragma unroll
                for (int nt = 0; nt < 4; ++nt)
                    acc[mt][nt] = __builtin_amdgcn_mfma_f32_16x16x32_bf16(
                        af[mt], bf[nt], acc[mt][nt], 0, 0, 0);
        }
    }

    float biasv[4];
#pragma unroll
    for (int nt = 0; nt < 4; ++nt)
        biasv[nt] = BIAS ? bias[tn0 + wn + nt * 16 + lm] : 0.0f;

    if (OUT == 2) {
        __syncthreads();
        unsigned short* T = lds;   // [128][128] bf16, col = m ^ ((n&15)<<3)
#pragma unroll
        for (int mt = 0; mt < 4; ++mt)
#pragma unroll
            for (int nt = 0; nt < 4; ++nt) {
                int n = wn + nt * 16 + lm;
                int m0 = wm + mt * 16 + q * 4;
                int col = m0 ^ ((n & 15) << 3);
                ushort4 pv;
                float v0 = acc[mt][nt][0] * scale; if (BIAS) v0 += biasv[nt];
                float v1 = acc[mt][nt][1] * scale; if (BIAS) v1 += biasv[nt];
                float v2 = acc[mt][nt][2] * scale; if (BIAS) v2 += biasv[nt];
                float v3 = acc[mt][nt][3] * scale; if (BIAS) v3 += biasv[nt];
                pv.x = f2b(v0); pv.y = f2b(v1); pv.z = f2b(v2); pv.w = f2b(v3);
                *(ushort4*)&T[n * 128 + col] = pv;
            }
        __syncthreads();
        unsigned short* Cb = (unsigned short*)C + (size_t)(tm0 >> 11) * strideC + (tm0 & 2047);
#pragma unroll
        for (int r8 = 0; r8 < 8; ++r8) {
            int idx = tid + 256 * r8;        // 0..2047 over 128 rows x 16 chunks
            int d = idx >> 4, c = idx & 15;
            int cs = (c ^ (d & 15)) << 3;    // inverse of the write swizzle
            short8 v = *(const short8*)&T[d * 128 + cs];
            *(short8*)&Cb[(size_t)(tn0 + d) * ldC + c * 8] = v;
        }
        return;
    }

#pragma unroll
    for (int mt = 0; mt < 4; ++mt) {
#pragma unroll
        for (int nt = 0; nt < 4; ++nt) {
            int gm = tm0 + wm + mt * 16 + q * 4;
            int gn = tn0 + wn + nt * 16 + lm;
#pragma unroll
            for (int r = 0; r < 4; ++r) {
                float v = acc[mt][nt][r] * scale;
                if (BIAS) v += biasv[nt];
                size_t idx = (size_t)bz * strideC + (size_t)(gm + r) * ldC + gn;
                if (OUT == 1) ((float*)C)[idx] = v;
                else          ((unsigned short*)C)[idx] = f2b(v);
            }
        }
    }
}

// ---------------- bf16 256x256 phase-split GEMM (T3+T5), proven r4 ----------------
// 512 threads = 8 waves (2M x 4N), per-wave 128x64, BK=64, 128 KB LDS.
// One tile = 256x64 bf16 = 16384 elements (32 KB). A bufs {0,16384}, B {32768,49152}.
// Invariants: disjoint double-buffer (stage t+1 into buf[(t+1)&1]); single
// vmcnt(0)+barrier drain per K-tile after ~3 phases of MFMA cover.
template <int MH>
__device__ __forceinline__ void mfma16(floatx4 (&acc)[8][4], const short8 (&af)[4],
                                       const short8 (&bf)[4]) {
#pragma unroll
    for (int m = 0; m < 4; ++m)
#pragma unroll
        for (int n = 0; n < 4; ++n)
            acc[MH * 4 + m][n] = __builtin_amdgcn_mfma_f32_16x16x32_bf16(
                af[m], bf[n], acc[MH * 4 + m][n], 0, 0, 0);
}

template <int NXB, int NYB>
__global__ __launch_bounds__(512, 2) void gemm_bt8(
    const unsigned short* __restrict__ A, int ldA, long long strideA,
    const unsigned short* __restrict__ B, int ldB, long long strideB,
    float* __restrict__ C, int ldC, long long strideC,
    float scale, int K) {
    __shared__ __align__(16) unsigned short lds[65536];   // A:2x32KB | B:2x32KB
    constexpr int TILE = 16384;                           // elements per tile buffer
    constexpr int BREG = 32768;                           // B region element offset

    int tid = threadIdx.x;
    int wave = tid >> 6, lane = tid & 63;
    int lm = lane & 15, q = lane >> 4;
    int wmi = wave >> 2, wni = wave & 3;

    unsigned flat = blockIdx.x;
    unsigned wg = (flat & 7u) * (gridDim.x >> 3) + (flat >> 3);
    int bx = wg % NXB;
    int rem = wg / NXB;
    int by = rem % NYB;
    int bz = rem / NYB;
    int tn0 = bx * 256, tm0 = by * 256;

    const unsigned short* Ab = A + (size_t)bz * strideA;
    const unsigned short* Bb = B + (size_t)bz * strideB;

    int srow8 = lane >> 3, s7 = lane & 7;
    const unsigned short* gA[4];
    const unsigned short* gB[4];
#pragma unroll
    for (int i = 0; i < 4; ++i) {
        int r = i * 64 + wave * 8 + srow8;
        int blk = s7 ^ (r & 7);
        gA[i] = Ab + (size_t)(tm0 + r) * ldA + blk * 8;
        gB[i] = Bb + (size_t)(tn0 + r) * ldB + blk * 8;
    }

    int nt = K >> 6;

    // prologue: stage tile 0 into buffer 0, full drain
#pragma unroll
    for (int i = 0; i < 4; ++i)
        __builtin_amdgcn_global_load_lds(AS_GLOBAL(gB[i]), AS_LOCAL(lds + BREG + i * 4096 + wave * 512), 16, 0, 0);
#pragma unroll
    for (int i = 0; i < 4; ++i)
        __builtin_amdgcn_global_load_lds(AS_GLOBAL(gA[i]), AS_LOCAL(lds + i * 4096 + wave * 512), 16, 0, 0);
#pragma unroll
    for (int i = 0; i < 4; ++i) { gA[i] += 64; gB[i] += 64; }   // -> tile 1

    asm volatile("s_waitcnt vmcnt(0)" ::: "memory");
    __builtin_amdgcn_s_barrier();

    floatx4 acc[8][4] = {};
    short8 bf0[4], bf1[4];
    short8 af[4];

    int aOff = (wmi * 128 + lm) * 64;       // element offset of this wave's A rows
    int bOff = (wni * 64 + lm) * 64;        // element offset of this wave's B rows
    int sl0 = (q ^ (lm & 7)) * 8;           // kk=0 chunk slot
    int sl1 = ((4 + q) ^ (lm & 7)) * 8;     // kk=1 chunk slot

    for (int t = 0; t < nt; ++t) {
        unsigned short* Ap = lds + (t & 1) * TILE;               // read buffers
        unsigned short* Bp = lds + BREG + (t & 1) * TILE;
        unsigned short* An = lds + ((t + 1) & 1) * TILE;         // stage buffers
        unsigned short* Bn = lds + BREG + ((t + 1) & 1) * TILE;
        bool pre = (t + 1) < nt;

        // ---- phase 1: all 8 B frags + A(mh0,kk0); issue B(t+1) ----
#pragma unroll
        for (int n = 0; n < 4; ++n) bf0[n] = *(const short8*)(Bp + bOff + n * 1024 + sl0);
#pragma unroll
        for (int n = 0; n < 4; ++n) bf1[n] = *(const short8*)(Bp + bOff + n * 1024 + sl1);
#pragma unroll
        for (int m = 0; m < 4; ++m) af[m] = *(const short8*)(Ap + aOff + m * 1024 + sl0);
        if (pre) {
#pragma unroll
            for (int i = 0; i < 4; ++i)
                __builtin_amdgcn_global_load_lds(AS_GLOBAL(gB[i]), AS_LOCAL(Bn + i * 4096 + wave * 512), 16, 0, 0);
        }
        __builtin_amdgcn_sched_barrier(0);
        __builtin_amdgcn_s_barrier();
        asm volatile("s_waitcnt lgkmcnt(0)" ::: "memory");
        __builtin_amdgcn_sched_barrier(0);
        __builtin_amdgcn_s_setprio(1);
        mfma16<0>(acc, af, bf0);
        __builtin_amdgcn_s_setprio(0);
        __builtin_amdgcn_s_barrier();

        // ---- phase 2: A(mh1,kk0); issue A(t+1) ----
#pragma unroll
        for (int m = 0; m < 4; ++m) af[m] = *(const short8*)(Ap + aOff + 4096 + m * 1024 + sl0);
        if (pre) {
#pragma unroll
            for (int i = 0; i < 4; ++i)
                __builtin_amdgcn_global_load_lds(AS_GLOBAL(gA[i]), AS_LOCAL(An + i * 4096 + wave * 512), 16, 0, 0);
#pragma unroll
            for (int i = 0; i < 4; ++i) { gA[i] += 64; gB[i] += 64; }
        }
        __builtin_amdgcn_sched_barrier(0);
        __builtin_amdgcn_s_barrier();
        asm volatile("s_waitcnt lgkmcnt(0)" ::: "memory");
        __builtin_amdgcn_sched_barrier(0);
        __builtin_amdgcn_s_setprio(1);
        mfma16<1>(acc, af, bf0);
        __builtin_amdgcn_s_setprio(0);
        __builtin_amdgcn_s_barrier();

        // ---- phase 3: A(mh0,kk1) ----
#pragma unroll
        for (int m = 0; m < 4; ++m) af[m] = *(const short8*)(Ap + aOff + m * 1024 + sl1);
        __builtin_amdgcn_sched_barrier(0);
        __builtin_amdgcn_s_barrier();
        asm volatile("s_waitcnt lgkmcnt(0)" ::: "memory");
        __builtin_amdgcn_sched_barrier(0);
        __builtin_amdgcn_s_setprio(1);
        mfma16<0>(acc, af, bf1);
        __builtin_amdgcn_s_setprio(0);
        __builtin_amdgcn_s_barrier();

        // ---- phase 4: A(mh1,kk1); drain staging, swap ----
#pragma unroll
        for (int m = 0; m < 4; ++m) af[m] = *(const short8*)(Ap + aOff + 4096 + m * 1024 + sl1);
        __builtin_amdgcn_sched_barrier(0);
        __builtin_amdgcn_s_barrier();
        asm volatile("s_waitcnt lgkmcnt(0)" ::: "memory");
        __builtin_amdgcn_sched_barrier(0);
        __builtin_amdgcn_s_setprio(1);
        mfma16<1>(acc, af, bf1);
        __builtin_amdgcn_s_setprio(0);
        asm volatile("s_waitcnt vmcnt(0)" ::: "memory");
        __builtin_amdgcn_s_barrier();
    }

    float* Cb = C + (size_t)bz * strideC;
#pragma unroll
    for (int m = 0; m < 8; ++m) {
#pragma unroll
        for (int n = 0; n < 4; ++n) {
            int gm = tm0 + wmi * 128 + m * 16 + q * 4;
            int gn = tn0 + wni * 64 + n * 16 + lm;
#pragma unroll
            for (int r = 0; r < 4; ++r)
                Cb[(size_t)(gm + r) * ldC + gn] = acc[m][n][r] * scale;
        }
    }
}

// ---------------- fp8 256x256 phase-split GEMM (mfma_scale 16x16x128) ----------------
// Same proven schedule/geometry as gemm_bt8: rows are 128 B with 8 XOR-swizzled
// 16 B chunks (byte-identical staging), tile = 256x128B = 32 KB, 2 phases per
// K=128 tile (16 MFMA each), disjoint double buffer, single vmcnt(0) drain per
// tile. Fragment chunk-pair (lo/hi) addressing lifted from the proven 128² fp8
// kernel. For the S-GEMM both operand panels are XCD-L2-resident -> the drain
// waits on L2-latency loads with ~1.5 MFMA phases of cover.
__device__ __forceinline__ void rd_f8(intx8& d, const unsigned char* p, int lo, int hi) {
    int4 L = *(const int4*)(p + lo);
    int4 H = *(const int4*)(p + hi);
    d[0] = L.x; d[1] = L.y; d[2] = L.z; d[3] = L.w;
    d[4] = H.x; d[5] = H.y; d[6] = H.z; d[7] = H.w;
}

template <bool BIAS, bool OUTFP8, int NXB, int NYB>
__global__ __launch_bounds__(512, 2) void gemm_f8_bt8(
    const unsigned char* __restrict__ A, int ldA, long long strideA,
    const unsigned char* __restrict__ B, int ldB, long long strideB,
    void* __restrict__ C, int ldC, long long strideC,
    const float* __restrict__ bias, float scale, int K) {
    __shared__ __align__(16) unsigned char lds[131072];   // A:2x32KB | B:2x32KB
    constexpr int TILE = 32768;                            // bytes per tile buffer
    constexpr int BREG = 65536;                            // B region byte offset

    int tid = threadIdx.x;
    int wave = tid >> 6, lane = tid & 63;
    int lm = lane & 15, q = lane >> 4;
    int q2 = q * 2;
    int wmi = wave >> 2, wni = wave & 3;

    unsigned flat = blockIdx.x;
    unsigned wg = (flat & 7u) * (gridDim.x >> 3) + (flat >> 3);
    int bx = wg % NXB;
    int rem = wg / NXB;
    int by = rem % NYB;
    int bz = rem / NYB;
    int tn0 = bx * 256, tm0 = by * 256;

    const unsigned char* Ab = A + (size_t)bz * strideA;
    const unsigned char* Bb = B + (size_t)bz * strideB;

    int srow8 = lane >> 3, s7 = lane & 7;
    const unsigned char* gA[4];
    const unsigned char* gB[4];
#pragma unroll
    for (int i = 0; i < 4; ++i) {
        int r = i * 64 + wave * 8 + srow8;
        int blk = s7 ^ (r & 7);
        gA[i] = Ab + (size_t)(tm0 + r) * ldA + blk * 16;
        gB[i] = Bb + (size_t)(tn0 + r) * ldB + blk * 16;
    }

    int nt = K >> 7;

    // prologue: stage tile 0 into buffer 0, full drain
#pragma unroll
    for (int i = 0; i < 4; ++i)
        __builtin_amdgcn_global_load_lds(AS_GLOBAL(gB[i]), AS_LOCAL(lds + BREG + i * 8192 + wave * 1024), 16, 0, 0);
#pragma unroll
    for (int i = 0; i < 4; ++i)
        __builtin_amdgcn_global_load_lds(AS_GLOBAL(gA[i]), AS_LOCAL(lds + i * 8192 + wave * 1024), 16, 0, 0);
#pragma unroll
    for (int i = 0; i < 4; ++i) { gA[i] += 128; gB[i] += 128; }   // -> tile 1

    asm volatile("s_waitcnt vmcnt(0)" ::: "memory");
    __builtin_amdgcn_s_barrier();

    floatx4 acc[8][4] = {};
    intx8 afr[4], bfr[4];

    int aOff = (wmi * 128 + lm) * 128;     // byte offset of this wave's A rows
    int bOff = (wni * 64 + lm) * 128;      // byte offset of this wave's B rows
    int lo = (q2 ^ (lm & 7)) << 4;
    int hi = ((q2 + 1) ^ (lm & 7)) << 4;

    for (int t = 0; t < nt; ++t) {
        unsigned char* Ap = lds + (t & 1) * TILE;
        unsigned char* Bp = lds + BREG + (t & 1) * TILE;
        unsigned char* An = lds + ((t + 1) & 1) * TILE;
        unsigned char* Bn = lds + BREG + ((t + 1) & 1) * TILE;
        bool pre = (t + 1) < nt;

        // ---- phase 1: all 4 B frags + A(mh0); issue B(t+1) ----
#pragma unroll
        for (int n = 0; n < 4; ++n) rd_f8(bfr[n], Bp + bOff + n * 2048, lo, hi);
#pragma unroll
        for (int m = 0; m < 4; ++m) rd_f8(afr[m], Ap + aOff + m * 2048, lo, hi);
        if (pre) {
#pragma unroll
            for (int i = 0; i < 4; ++i)
                __builtin_amdgcn_global_load_lds(AS_GLOBAL(gB[i]), AS_LOCAL(Bn + i * 8192 + wave * 1024), 16, 0, 0);
        }
        __builtin_amdgcn_sched_barrier(0);
        __builtin_amdgcn_s_barrier();
        asm volatile("s_waitcnt lgkmcnt(0)" ::: "memory");
        __builtin_amdgcn_sched_barrier(0);
        __builtin_amdgcn_s_setprio(1);
#pragma unroll
        for (int m = 0; m < 4; ++m)
#pragma unroll
            for (int n = 0; n < 4; ++n)
                acc[m][n] = __builtin_amdgcn_mfma_scale_f32_16x16x128_f8f6f4(
                    afr[m], bfr[n], acc[m][n], 0, 0, 0, 0x7f7f7f7f, 0, 0x7f7f7f7f);
        __builtin_amdgcn_s_setprio(0);
        __builtin_amdgcn_s_barrier();

        // ---- phase 2: A(mh1); issue A(t+1); drain, swap ----
#pragma unroll
        for (int m = 0; m < 4; ++m) rd_f8(afr[m], Ap + aOff + 8192 + m * 2048, lo, hi);
        if (pre) {
#pragma unroll
            for (int i = 0; i < 4; ++i)
                __builtin_amdgcn_global_load_lds(AS_GLOBAL(gA[i]), AS_LOCAL(An + i * 8192 + wave * 1024), 16, 0, 0);
#pragma unroll
            for (int i = 0; i < 4; ++i) { gA[i] += 128; gB[i] += 128; }
        }
        __builtin_amdgcn_sched_barrier(0);
        __builtin_amdgcn_s_barrier();
        asm volatile("s_waitcnt lgkmcnt(0)" ::: "memory");
        __builtin_amdgcn_sched_barrier(0);
        __builtin_amdgcn_s_setprio(1);
#pragma unroll
        for (int m = 0; m < 4; ++m)
#pragma unroll
            for (int n = 0; n < 4; ++n)
                acc[4 + m][n] = __builtin_amdgcn_mfma_scale_f32_16x16x128_f8f6f4(
                    afr[m], bfr[n], acc[4 + m][n], 0, 0, 0, 0x7f7f7f7f, 0, 0x7f7f7f7f);
        __builtin_amdgcn_s_setprio(0);
        asm volatile("s_waitcnt vmcnt(0)" ::: "memory");
        __builtin_amdgcn_s_barrier();
    }

    float biasv[4];
#pragma unroll
    for (int n = 0; n < 4; ++n)
        biasv[n] = BIAS ? bias[tn0 + wni * 64 + n * 16 + lm] : 0.0f;
#pragma unroll
    for (int m = 0; m < 8; ++m) {
#pragma unroll
        for (int n = 0; n < 4; ++n) {
            int gm = tm0 + wmi * 128 + m * 16 + q * 4;
            int gn = tn0 + wni * 64 + n * 16 + lm;
#pragma unroll
            for (int r = 0; r < 4; ++r) {
                float v = acc[m][n][r] * scale;
                if (BIAS) v += biasv[n];
                size_t idx = (size_t)bz * strideC + (size_t)(gm + r) * ldC + gn;
                if (OUTFP8) ((unsigned char*)C)[idx] = f2fp8(v);
                else        ((unsigned short*)C)[idx] = f2b(v);
            }
        }
    }
}

extern "C" void kernel_launch(void* const* d_in, const int* in_sizes, int n_in,
                              void* d_out, int out_size, void* d_ws, size_t ws_size,
                              hipStream_t stream) {
    const float* x    = (const float*)d_in[0];   // [8,2048,1024]
    const int*   mask = (const int*)d_in[1];     // [8,2048,2048]
    const float* Wqkv = (const float*)d_in[2];   // [1024,3072]
    const float* bqkv = (const float*)d_in[3];   // [3072]
    const float* Wout = (const float*)d_in[4];   // [1024,1024]
    const float* bout = (const float*)d_in[5];   // [1024]
    float* out = (float*)d_out;                  // [8,2048,1024]

    char* w = (char*)d_ws;
    unsigned short* x_bf  = (unsigned short*)(w);              // 33,554,432
    unsigned char*  x_f8  = (unsigned char*)(w + 33554432);    // 16,777,216
    unsigned char*  QKf8  = (unsigned char*)(w + 50331648);    // 33,554,432  [16384][2048]: Q cols 0..1023, K cols 1024..2047
    unsigned short* VpT   = (unsigned short*)(w + 117440512);  // 33,554,432  [8][1024][2048]
    unsigned short* S     = (unsigned short*)(w + 150994944);  // 67,108,864
    unsigned char*  WqkT8 = (unsigned char*)(w + 218103808);   //  2,097,152
    unsigned short* WoT   = (unsigned short*)(w + 220200960);  //  2,097,152
    unsigned short* Wv_bf = (unsigned short*)(w + 222298112);  //  2,097,152
    unsigned short* WvoT  = (unsigned short*)(w + 224395264);  //  2,097,152
    float*          bvo   = (float*)(w + 226492416);           //      4,096  -> 226.5 MB total

    // 1) input casts / weight prep
    cast_x<<<16384, 256, 0, stream>>>(x, x_bf, (unsigned int*)x_f8, 4194304);
    transpose_f32_fp8_qk<<<dim3(64, 32), dim3(32, 8), 0, stream>>>(Wqkv, WqkT8);
    transpose_f32_bf16<<<dim3(32, 32), dim3(32, 8), 0, stream>>>(Wout, WoT, 1024, 1024);
    cast_wv<<<1024, 256, 0, stream>>>(Wqkv, Wv_bf);
    bvo_kernel<<<256, 256, 0, stream>>>(WoT, bqkv, bout, bvo);

    // 2) WvoT = (Wv @ Wout)^T : C[e][d] = sum_h WoT[e][h] * Wv[d][h]   (grid 8x8 -> 64)
    gemm_bt<4, false, 0, 3, 3><<<64, 256, 0, stream>>>(
        WoT, 1024, 0, Wv_bf, 1024, 0, WvoT, 1024, 0, nullptr, 1.0f, 1024);

    // 3) QK projection in fp8, 256^2 phase-split: [16384][2048] = x_f8 @ WqkT8^T + bqkv
    //    grid 8x64 -> 512; XCD k owns token-chunk [2048k..2048k+2048), WqkT8 L2-resident
    gemm_f8_bt8<true, true, 8, 64><<<512, 512, 0, stream>>>(
        x_f8, 1024, 0, WqkT8, 1024, 0, QKf8, 2048, 0, bqkv, 1.0f, 1024);

    // 4) V'^T = (x @ Wvo + bvo)^T, transposed epilogue writes VpT [8][1024][2048] directly
    gemm_bt<5, true, 2, 3, 7><<<1024, 256, 0, stream>>>(
        x_bf, 1024, 0, WvoT, 1024, 0, VpT, 2048, 1024LL * 2048, bvo, 1.0f, 1024);

    // 5) S = Q @ K^T / sqrt(D) in fp8, 256^2 phase-split -> bf16 [8][2048][2048]
    //    grid 8x8x8 -> 512; XCD k <-> batch k (Q,K panels 2 MB each, L2-resident)
    gemm_f8_bt8<false, false, 8, 8><<<512, 512, 0, stream>>>(
        QKf8, 2048, 2048LL * 2048, QKf8 + 1024, 2048, 2048LL * 2048,
        S, 2048, 2048LL * 2048, nullptr, 0.03125f, 1024);

    // 6) softmax -> mask -> softmax, in place
    softmax2_kernel<<<4096, 256, 0, stream>>>(S, mask);

    // 7) out = P @ V' -> fp32 d_out, 256^2 phase-split kernel
    //    grid 4x8x8 = 256 blocks = 1/CU; XCD k <-> batch k
    gemm_bt8<4, 8><<<256, 512, 0, stream>>>(
        S, 2048, 2048LL * 2048, VpT, 2048, 1024LL * 2048,
        out, 1024, 2048LL * 1024, 1.0f, 2048);
}

// Round 6
// 495.834 us; speedup vs baseline: 1.1465x; 1.0070x over previous
//
#include <hip/hip_runtime.h>
#include <hip/hip_bf16.h>

typedef __attribute__((ext_vector_type(8))) short short8;
typedef __attribute__((ext_vector_type(4))) float floatx4;
typedef __attribute__((ext_vector_type(8))) int intx8;

#define AS_GLOBAL(p) ((const __attribute__((address_space(1))) void*)(p))
#define AS_LOCAL(p)  ((__attribute__((address_space(3))) void*)(p))

__device__ __forceinline__ float b2f(unsigned short u) {
    union { unsigned int u; float f; } c; c.u = ((unsigned int)u) << 16; return c.f;
}
__device__ __forceinline__ unsigned short f2b(float f) {
    union { float f; unsigned int u; } c; c.f = f;
    unsigned int u = c.u;
    unsigned int r = (u + 0x7fffu + ((u >> 16) & 1u)) >> 16;
    return (unsigned short)r;
}
__device__ __forceinline__ unsigned char f2fp8(float v) {
    return (unsigned char)(__builtin_amdgcn_cvt_pk_fp8_f32(v, v, 0, false) & 0xff);
}

// ---------------- cast x: fp32 -> bf16 AND fp8(e4m3) in one pass ----------------
__global__ __launch_bounds__(256) void cast_x(
    const float* __restrict__ in, unsigned short* __restrict__ xbf,
    unsigned int* __restrict__ xf8, int n4) {
    int i = blockIdx.x * 256 + threadIdx.x;
    if (i >= n4) return;
    float4 v = ((const float4*)in)[i];
    ushort4 o;
    o.x = f2b(v.x); o.y = f2b(v.y); o.z = f2b(v.z); o.w = f2b(v.w);
    ((ushort4*)xbf)[i] = o;
    int p = __builtin_amdgcn_cvt_pk_fp8_f32(v.x, v.y, 0, false);
    p = __builtin_amdgcn_cvt_pk_fp8_f32(v.z, v.w, p, true);
    xf8[i] = (unsigned int)p;
}

// ---------------- transpose fp32 [R][C] -> bf16 [C][R] (weights, small) ----------------
__global__ __launch_bounds__(256) void transpose_f32_bf16(
    const float* __restrict__ in, unsigned short* __restrict__ out, int R, int C) {
    __shared__ float t[32][33];
    int c0 = blockIdx.x * 32, r0 = blockIdx.y * 32;
    int tx = threadIdx.x, ty = threadIdx.y;
#pragma unroll
    for (int k = 0; k < 32; k += 8)
        t[ty + k][tx] = in[(size_t)(r0 + ty + k) * C + c0 + tx];
    __syncthreads();
#pragma unroll
    for (int k = 0; k < 32; k += 8)
        out[(size_t)(c0 + ty + k) * R + r0 + tx] = f2b(t[tx][ty + k]);
}

// ---------------- transpose Wqkv[:, :2048] fp32 [1024][3072] -> fp8 [2048][1024] ----------------
__global__ __launch_bounds__(256) void transpose_f32_fp8_qk(
    const float* __restrict__ in, unsigned char* __restrict__ out) {
    __shared__ float t[32][33];
    int c0 = blockIdx.x * 32, r0 = blockIdx.y * 32;   // c: 0..2048, r: 0..1024
    int tx = threadIdx.x, ty = threadIdx.y;
#pragma unroll
    for (int k = 0; k < 32; k += 8)
        t[ty + k][tx] = in[(size_t)(r0 + ty + k) * 3072 + c0 + tx];
    __syncthreads();
#pragma unroll
    for (int k = 0; k < 32; k += 8)
        out[(size_t)(c0 + ty + k) * 1024 + r0 + tx] = f2fp8(t[tx][ty + k]);
}

// ---------------- Wv slice: fp32 Wqkv[:,2048:3072] -> bf16 [1024][1024] ----------------
__global__ __launch_bounds__(256) void cast_wv(
    const float* __restrict__ in, unsigned short* __restrict__ out) {
    int i = blockIdx.x * 256 + threadIdx.x;   // over 262144 float4s
    int d = i >> 8, rem = (i & 255) * 4;
    float4 v = *(const float4*)&in[(size_t)d * 3072 + 2048 + rem];
    ushort4 o;
    o.x = f2b(v.x); o.y = f2b(v.y); o.z = f2b(v.z); o.w = f2b(v.w);
    *(ushort4*)&out[(size_t)d * 1024 + rem] = o;
}

// ---------------- bvo[e] = sum_h bqkv[2048+h]*WoT[e][h] + bout[e] ----------------
__global__ __launch_bounds__(256) void bvo_kernel(
    const unsigned short* __restrict__ WoT, const float* __restrict__ bqkv,
    const float* __restrict__ bout, float* __restrict__ bvo) {
    int wv = threadIdx.x >> 6, lane = threadIdx.x & 63;
    int e = blockIdx.x * 4 + wv;
    const unsigned short* row = WoT + (size_t)e * 1024;
    float s = 0.f;
    for (int h = lane; h < 1024; h += 64) s += b2f(row[h]) * bqkv[2048 + h];
#pragma unroll
    for (int o = 32; o; o >>= 1) s += __shfl_xor(s, o);
    if (lane == 0) bvo[e] = s + bout[e];
}

// ---------------- double softmax + mask, in place on S (bf16) ----------------
__global__ __launch_bounds__(256) void softmax2_kernel(
    unsigned short* __restrict__ S, const int* __restrict__ mask) {
    const int N = 2048;
    int wv = threadIdx.x >> 6, lane = threadIdx.x & 63;
    size_t row = (size_t)blockIdx.x * 4 + wv;
    unsigned short* srow = S + row * N;
    const int* mrow = mask + row * N;

    float e1[32];
    float l = 0.f;
#pragma unroll
    for (int i = 0; i < 4; ++i) {
        uint4 raw = ((const uint4*)srow)[lane + 64 * i];
        unsigned v[4] = { raw.x, raw.y, raw.z, raw.w };
#pragma unroll
        for (int j = 0; j < 4; ++j) {
            float a = b2f((unsigned short)(v[j] & 0xffff));
            float bb = b2f((unsigned short)(v[j] >> 16));
            float ea = __expf(a), eb = __expf(bb);
            e1[i * 8 + 2 * j] = ea; e1[i * 8 + 2 * j + 1] = eb;
            l += ea + eb;
        }
    }
#pragma unroll
    for (int o = 32; o; o >>= 1) l += __shfl_xor(l, o);
    float invl = 1.0f / l;

    float e2[32];
    float z = 0.f;
#pragma unroll
    for (int i = 0; i < 4; ++i) {
        uint4 m0 = ((const uint4*)mrow)[2 * (lane + 64 * i)];
        uint4 m1 = ((const uint4*)mrow)[2 * (lane + 64 * i) + 1];
        int mk[8] = { (int)m0.x, (int)m0.y, (int)m0.z, (int)m0.w,
                      (int)m1.x, (int)m1.y, (int)m1.z, (int)m1.w };
#pragma unroll
        for (int j = 0; j < 8; ++j) {
            float w1 = e1[i * 8 + j] * invl;
            float e = mk[j] ? __expf(w1) : 0.0f;
            e2[i * 8 + j] = e; z += e;
        }
    }
#pragma unroll
    for (int o = 32; o; o >>= 1) z += __shfl_xor(z, o);
    float invz = (z > 0.f) ? 1.0f / z : 0.0f;
    float fallback = 1.0f / N;
#pragma unroll
    for (int i = 0; i < 4; ++i) {
        float p[8];
#pragma unroll
        for (int j = 0; j < 8; ++j)
            p[j] = (z > 0.f) ? e2[i * 8 + j] * invz : fallback;
        uint4 o;
        o.x = (unsigned)f2b(p[0]) | ((unsigned)f2b(p[1]) << 16);
        o.y = (unsigned)f2b(p[2]) | ((unsigned)f2b(p[3]) << 16);
        o.z = (unsigned)f2b(p[4]) | ((unsigned)f2b(p[5]) << 16);
        o.w = (unsigned)f2b(p[6]) | ((unsigned)f2b(p[7]) << 16);
        ((uint4*)srow)[lane + 64 * i] = o;
    }
}

// ---------------- bf16 GEMM, B in [n][k] layout, m97-style ----------------
// OUT: 0 = bf16 C[m][n], 1 = f32 C[m][n], 2 = bf16 transposed VpT-write:
//      C[batch][n][m] with batch = tm0>>11 (M is flattened tokens, 2048/batch).
template <int TAG, bool BIAS, int OUT, int XS, int YS>
__global__ __launch_bounds__(256) void gemm_bt(
    const unsigned short* __restrict__ A, int ldA, long long strideA,
    const unsigned short* __restrict__ B, int ldB, long long strideB,
    void* __restrict__ C, int ldC, long long strideC,
    const float* __restrict__ bias, float scale, int K) {
    __shared__ __align__(16) unsigned short lds[2 * 128 * 64];
    unsigned short* At = lds;
    unsigned short* Bt = lds + 128 * 64;

    // XCD swizzle: nwg % 8 == 0 for all launches (bijective chunked remap)
    unsigned flat = blockIdx.x;
    unsigned wg = (flat & 7u) * (gridDim.x >> 3) + (flat >> 3);
    int bx = wg & ((1u << XS) - 1u);
    int by = (wg >> XS) & ((1u << YS) - 1u);
    int bz = wg >> (XS + YS);

    const unsigned short* Ab = A + (size_t)bz * strideA;
    const unsigned short* Bb = B + (size_t)bz * strideB;
    int tn0 = bx * 128;
    int tm0 = by * 128;
    int tid = threadIdx.x;
    int wave = tid >> 6, lane = tid & 63;
    int lm = lane & 15, q = lane >> 4;
    int wm = (wave >> 1) * 64, wn = (wave & 1) * 64;

    int srow = lane >> 3;
    int sblk = lane & 7;

    floatx4 acc[4][4] = {};

    for (int k0 = 0; k0 < K; k0 += 64) {
        __syncthreads();
#pragma unroll
        for (int i = 0; i < 4; ++i) {
            int chunk = wave * 4 + i;
            int r = chunk * 8 + srow;
            int blk = sblk ^ (r & 7);
            const unsigned short* ga = Ab + (size_t)(tm0 + r) * ldA + (k0 + blk * 8);
            __builtin_amdgcn_global_load_lds(AS_GLOBAL(ga), AS_LOCAL(At + chunk * 512), 16, 0, 0);
            const unsigned short* gb = Bb + (size_t)(tn0 + r) * ldB + (k0 + blk * 8);
            __builtin_amdgcn_global_load_lds(AS_GLOBAL(gb), AS_LOCAL(Bt + chunk * 512), 16, 0, 0);
        }
        __syncthreads();
#pragma unroll
        for (int kk = 0; kk < 2; ++kk) {
            short8 af[4], bf[4];
#pragma unroll
            for (int mt = 0; mt < 4; ++mt) {
                int r = wm + mt * 16 + lm;
                af[mt] = *(const short8*)(At + r * 64 + (((kk * 4 + q) ^ (r & 7)) * 8));
            }
#pragma unroll
            for (int nt = 0; nt < 4; ++nt) {
                int r = wn + nt * 16 + lm;
                bf[nt] = *(const short8*)(Bt + r * 64 + (((kk * 4 + q) ^ (r & 7)) * 8));
            }
#pragma unroll
            for (int mt = 0; mt < 4; ++mt)
#pragma unroll
                for (int nt = 0; nt < 4; ++nt)
                    acc[mt][nt] = __builtin_amdgcn_mfma_f32_16x16x32_bf16(
                        af[mt], bf[nt], acc[mt][nt], 0, 0, 0);
        }
    }

    float biasv[4];
#pragma unroll
    for (int nt = 0; nt < 4; ++nt)
        biasv[nt] = BIAS ? bias[tn0 + wn + nt * 16 + lm] : 0.0f;

    if (OUT == 2) {
        __syncthreads();
        unsigned short* T = lds;   // [128][128] bf16, col = m ^ ((n&15)<<3)
#pragma unroll
        for (int mt = 0; mt < 4; ++mt)
#pragma unroll
            for (int nt = 0; nt < 4; ++nt) {
                int n = wn + nt * 16 + lm;
                int m0 = wm + mt * 16 + q * 4;
                int col = m0 ^ ((n & 15) << 3);
                ushort4 pv;
                float v0 = acc[mt][nt][0] * scale; if (BIAS) v0 += biasv[nt];
                float v1 = acc[mt][nt][1] * scale; if (BIAS) v1 += biasv[nt];
                float v2 = acc[mt][nt][2] * scale; if (BIAS) v2 += biasv[nt];
                float v3 = acc[mt][nt][3] * scale; if (BIAS) v3 += biasv[nt];
                pv.x = f2b(v0); pv.y = f2b(v1); pv.z = f2b(v2); pv.w = f2b(v3);
                *(ushort4*)&T[n * 128 + col] = pv;
            }
        __syncthreads();
        unsigned short* Cb = (unsigned short*)C + (size_t)(tm0 >> 11) * strideC + (tm0 & 2047);
#pragma unroll
        for (int r8 = 0; r8 < 8; ++r8) {
            int idx = tid + 256 * r8;        // 0..2047 over 128 rows x 16 chunks
            int d = idx >> 4, c = idx & 15;
            int cs = (c ^ (d & 15)) << 3;    // inverse of the write swizzle
            short8 v = *(const short8*)&T[d * 128 + cs];
            *(short8*)&Cb[(size_t)(tn0 + d) * ldC + c * 8] = v;
        }
        return;
    }

#pragma unroll
    for (int mt = 0; mt < 4; ++mt) {
#pragma unroll
        for (int nt = 0; nt < 4; ++nt) {
            int gm = tm0 + wm + mt * 16 + q * 4;
            int gn = tn0 + wn + nt * 16 + lm;
#pragma unroll
            for (int r = 0; r < 4; ++r) {
                float v = acc[mt][nt][r] * scale;
                if (BIAS) v += biasv[nt];
                size_t idx = (size_t)bz * strideC + (size_t)(gm + r) * ldC + gn;
                if (OUT == 1) ((float*)C)[idx] = v;
                else          ((unsigned short*)C)[idx] = f2b(v);
            }
        }
    }
}

// ---------------- bf16 256x256 phase-split GEMM, counted-vmcnt (T3+T4+T5) ----------------
// 512 threads = 8 waves (2M x 4N), per-wave 128x64, BK=64, 128 KB LDS.
// One tile = 256x64 bf16 = 16384 elements (32 KB). A bufs {0,16384}, B {32768,49152}.
// COUNTED-VMCNT SCHEDULE (r1-derived, safety re-proven):
//  * tile t reads buf[t&1]; B frags are consumed ONLY in phase 1 (held in regs),
//    A frags per phase. So:
//    - B(t+2) -> B buf[t&1] issues in phase 2, i.e. AFTER phase-1's end barrier,
//      at which point every wave has lgkmcnt(0)-drained its Bp ds_reads.
//    - A(t+2) -> A buf[t&1] issues after phase-4's end barrier (all Ap reads drained).
//  * end-of-tile wait: per wave, outstanding = {t+1: 8 oldest, t+2: 8 newest};
//    s_waitcnt vmcnt(8) drains exactly t+1's loads, leaves t+2's in flight
//    across the barrier (T4: never drain to 0 in steady state).
//  * t = nt-2: no t+2 issue -> vmcnt(0) (vmcnt(8) would be a no-op with only 8
//    outstanding). t = nt-1: no wait needed.  All branches uniform.
template <int MH>
__device__ __forceinline__ void mfma16(floatx4 (&acc)[8][4], const short8 (&af)[4],
                                       const short8 (&bf)[4]) {
#pragma unroll
    for (int m = 0; m < 4; ++m)
#pragma unroll
        for (int n = 0; n < 4; ++n)
            acc[MH * 4 + m][n] = __builtin_amdgcn_mfma_f32_16x16x32_bf16(
                af[m], bf[n], acc[MH * 4 + m][n], 0, 0, 0);
}

template <int NXB, int NYB>
__global__ __launch_bounds__(512, 2) void gemm_bt8(
    const unsigned short* __restrict__ A, int ldA, long long strideA,
    const unsigned short* __restrict__ B, int ldB, long long strideB,
    float* __restrict__ C, int ldC, long long strideC,
    float scale, int K) {
    __shared__ __align__(16) unsigned short lds[65536];   // A:2x32KB | B:2x32KB
    constexpr int TILE = 16384;                           // elements per tile buffer
    constexpr int BREG = 32768;                           // B region element offset

    int tid = threadIdx.x;
    int wave = tid >> 6, lane = tid & 63;
    int lm = lane & 15, q = lane >> 4;
    int wmi = wave >> 2, wni = wave & 3;

    unsigned flat = blockIdx.x;
    unsigned wg = (flat & 7u) * (gridDim.x >> 3) + (flat >> 3);
    int bx = wg % NXB;
    int rem = wg / NXB;
    int by = rem % NYB;
    int bz = rem / NYB;
    int tn0 = bx * 256, tm0 = by * 256;

    const unsigned short* Ab = A + (size_t)bz * strideA;
    const unsigned short* Bb = B + (size_t)bz * strideB;

    int srow8 = lane >> 3, s7 = lane & 7;
    const unsigned short* gA[4];
    const unsigned short* gB[4];
#pragma unroll
    for (int i = 0; i < 4; ++i) {
        int r = i * 64 + wave * 8 + srow8;
        int blk = s7 ^ (r & 7);
        gA[i] = Ab + (size_t)(tm0 + r) * ldA + blk * 8;
        gB[i] = Bb + (size_t)(tn0 + r) * ldB + blk * 8;
    }

    int nt = K >> 6;   // caller guarantees nt >= 2

    // prologue: stage tile 0 (buf0) and tile 1 (buf1); drain tile 0 only
#pragma unroll
    for (int i = 0; i < 4; ++i)
        __builtin_amdgcn_global_load_lds(AS_GLOBAL(gB[i]), AS_LOCAL(lds + BREG + i * 4096 + wave * 512), 16, 0, 0);
#pragma unroll
    for (int i = 0; i < 4; ++i)
        __builtin_amdgcn_global_load_lds(AS_GLOBAL(gA[i]), AS_LOCAL(lds + i * 4096 + wave * 512), 16, 0, 0);
#pragma unroll
    for (int i = 0; i < 4; ++i)
        __builtin_amdgcn_global_load_lds(AS_GLOBAL(gB[i] + 64), AS_LOCAL(lds + BREG + TILE + i * 4096 + wave * 512), 16, 0, 0);
#pragma unroll
    for (int i = 0; i < 4; ++i)
        __builtin_amdgcn_global_load_lds(AS_GLOBAL(gA[i] + 64), AS_LOCAL(lds + TILE + i * 4096 + wave * 512), 16, 0, 0);
#pragma unroll
    for (int i = 0; i < 4; ++i) { gA[i] += 128; gB[i] += 128; }   // -> tile 2

    asm volatile("s_waitcnt vmcnt(8)" ::: "memory");
    __builtin_amdgcn_s_barrier();

    floatx4 acc[8][4] = {};
    short8 bf0[4], bf1[4];
    short8 af[4];

    int aOff = (wmi * 128 + lm) * 64;       // element offset of this wave's A rows
    int bOff = (wni * 64 + lm) * 64;        // element offset of this wave's B rows
    int sl0 = (q ^ (lm & 7)) * 8;           // kk=0 chunk slot
    int sl1 = ((4 + q) ^ (lm & 7)) * 8;     // kk=1 chunk slot

    for (int t = 0; t < nt; ++t) {
        unsigned short* Ap = lds + (t & 1) * TILE;            // read buffers; also
        unsigned short* Bp = lds + BREG + (t & 1) * TILE;     // stage targets for t+2
        bool pre = (t + 2) < nt;

        // ---- phase 1: all 8 B frags + A(mh0,kk0) ----
#pragma unroll
        for (int n = 0; n < 4; ++n) bf0[n] = *(const short8*)(Bp + bOff + n * 1024 + sl0);
#pragma unroll
        for (int n = 0; n < 4; ++n) bf1[n] = *(const short8*)(Bp + bOff + n * 1024 + sl1);
#pragma unroll
        for (int m = 0; m < 4; ++m) af[m] = *(const short8*)(Ap + aOff + m * 1024 + sl0);
        __builtin_amdgcn_sched_barrier(0);
        __builtin_amdgcn_s_barrier();
        asm volatile("s_waitcnt lgkmcnt(0)" ::: "memory");
        __builtin_amdgcn_sched_barrier(0);
        __builtin_amdgcn_s_setprio(1);
        mfma16<0>(acc, af, bf0);
        __builtin_amdgcn_s_setprio(0);
        __builtin_amdgcn_s_barrier();
        // (all waves past this barrier => every Bp ds_read has completed)

        // ---- phase 2: A(mh1,kk0); issue B(t+2) into Bp (B reads done) ----
#pragma unroll
        for (int m = 0; m < 4; ++m) af[m] = *(const short8*)(Ap + aOff + 4096 + m * 1024 + sl0);
        if (pre) {
#pragma unroll
            for (int i = 0; i < 4; ++i)
                __builtin_amdgcn_global_load_lds(AS_GLOBAL(gB[i]), AS_LOCAL(Bp + i * 4096 + wave * 512), 16, 0, 0);
        }
        __builtin_amdgcn_sched_barrier(0);
        __builtin_amdgcn_s_barrier();
        asm volatile("s_waitcnt lgkmcnt(0)" ::: "memory");
        __builtin_amdgcn_sched_barrier(0);
        __builtin_amdgcn_s_setprio(1);
        mfma16<1>(acc, af, bf0);
        __builtin_amdgcn_s_setprio(0);
        __builtin_amdgcn_s_barrier();

        // ---- phase 3: A(mh0,kk1) ----
#pragma unroll
        for (int m = 0; m < 4; ++m) af[m] = *(const short8*)(Ap + aOff + m * 1024 + sl1);
        __builtin_amdgcn_sched_barrier(0);
        __builtin_amdgcn_s_barrier();
        asm volatile("s_waitcnt lgkmcnt(0)" ::: "memory");
        __builtin_amdgcn_sched_barrier(0);
        __builtin_amdgcn_s_setprio(1);
        mfma16<0>(acc, af, bf1);
        __builtin_amdgcn_s_setprio(0);
        __builtin_amdgcn_s_barrier();

        // ---- phase 4: A(mh1,kk1) ----
#pragma unroll
        for (int m = 0; m < 4; ++m) af[m] = *(const short8*)(Ap + aOff + 4096 + m * 1024 + sl1);
        __builtin_amdgcn_sched_barrier(0);
        __builtin_amdgcn_s_barrier();
        asm volatile("s_waitcnt lgkmcnt(0)" ::: "memory");
        __builtin_amdgcn_sched_barrier(0);
        __builtin_amdgcn_s_setprio(1);
        mfma16<1>(acc, af, bf1);
        __builtin_amdgcn_s_setprio(0);
        __builtin_amdgcn_s_barrier();
        // (all waves past this barrier => every Ap ds_read has completed)

        // ---- end of tile: issue A(t+2) into Ap; counted wait for t+1 ----
        if (pre) {
#pragma unroll
            for (int i = 0; i < 4; ++i)
                __builtin_amdgcn_global_load_lds(AS_GLOBAL(gA[i]), AS_LOCAL(Ap + i * 4096 + wave * 512), 16, 0, 0);
#pragma unroll
            for (int i = 0; i < 4; ++i) { gA[i] += 64; gB[i] += 64; }
            asm volatile("s_waitcnt vmcnt(8)" ::: "memory");   // drain t+1, keep t+2 in flight
            __builtin_amdgcn_s_barrier();
        } else if (t + 1 < nt) {
            asm volatile("s_waitcnt vmcnt(0)" ::: "memory");   // tail: drain t+1
            __builtin_amdgcn_s_barrier();
        }
    }

    float* Cb = C + (size_t)bz * strideC;
#pragma unroll
    for (int m = 0; m < 8; ++m) {
#pragma unroll
        for (int n = 0; n < 4; ++n) {
            int gm = tm0 + wmi * 128 + m * 16 + q * 4;
            int gn = tn0 + wni * 64 + n * 16 + lm;
#pragma unroll
            for (int r = 0; r < 4; ++r)
                Cb[(size_t)(gm + r) * ldC + gn] = acc[m][n][r] * scale;
        }
    }
}

// ---------------- fp8 256x256 phase-split GEMM (mfma_scale 16x16x128) ----------------
// Proven r5 state: disjoint double buffer, single vmcnt(0) drain per K-tile.
__device__ __forceinline__ void rd_f8(intx8& d, const unsigned char* p, int lo, int hi) {
    int4 L = *(const int4*)(p + lo);
    int4 H = *(const int4*)(p + hi);
    d[0] = L.x; d[1] = L.y; d[2] = L.z; d[3] = L.w;
    d[4] = H.x; d[5] = H.y; d[6] = H.z; d[7] = H.w;
}

template <bool BIAS, bool OUTFP8, int NXB, int NYB>
__global__ __launch_bounds__(512, 2) void gemm_f8_bt8(
    const unsigned char* __restrict__ A, int ldA, long long strideA,
    const unsigned char* __restrict__ B, int ldB, long long strideB,
    void* __restrict__ C, int ldC, long long strideC,
    const float* __restrict__ bias, float scale, int K) {
    __shared__ __align__(16) unsigned char lds[131072];   // A:2x32KB | B:2x32KB
    constexpr int TILE = 32768;                            // bytes per tile buffer
    constexpr int BREG = 65536;                            // B region byte offset

    int tid = threadIdx.x;
    int wave = tid >> 6, lane = tid & 63;
    int lm = lane & 15, q = lane >> 4;
    int q2 = q * 2;
    int wmi = wave >> 2, wni = wave & 3;

    unsigned flat = blockIdx.x;
    unsigned wg = (flat & 7u) * (gridDim.x >> 3) + (flat >> 3);
    int bx = wg % NXB;
    int rem = wg / NXB;
    int by = rem % NYB;
    int bz = rem / NYB;
    int tn0 = bx * 256, tm0 = by * 256;

    const unsigned char* Ab = A + (size_t)bz * strideA;
    const unsigned char* Bb = B + (size_t)bz * strideB;

    int srow8 = lane >> 3, s7 = lane & 7;
    const unsigned char* gA[4];
    const unsigned char* gB[4];
#pragma unroll
    for (int i = 0; i < 4; ++i) {
        int r = i * 64 + wave * 8 + srow8;
        int blk = s7 ^ (r & 7);
        gA[i] = Ab + (size_t)(tm0 + r) * ldA + blk * 16;
        gB[i] = Bb + (size_t)(tn0 + r) * ldB + blk * 16;
    }

    int nt = K >> 7;

    // prologue: stage tile 0 into buffer 0, full drain
#pragma unroll
    for (int i = 0; i < 4; ++i)
        __builtin_amdgcn_global_load_lds(AS_GLOBAL(gB[i]), AS_LOCAL(lds + BREG + i * 8192 + wave * 1024), 16, 0, 0);
#pragma unroll
    for (int i = 0; i < 4; ++i)
        __builtin_amdgcn_global_load_lds(AS_GLOBAL(gA[i]), AS_LOCAL(lds + i * 8192 + wave * 1024), 16, 0, 0);
#pragma unroll
    for (int i = 0; i < 4; ++i) { gA[i] += 128; gB[i] += 128; }   // -> tile 1

    asm volatile("s_waitcnt vmcnt(0)" ::: "memory");
    __builtin_amdgcn_s_barrier();

    floatx4 acc[8][4] = {};
    intx8 afr[4], bfr[4];

    int aOff = (wmi * 128 + lm) * 128;     // byte offset of this wave's A rows
    int bOff = (wni * 64 + lm) * 128;      // byte offset of this wave's B rows
    int lo = (q2 ^ (lm & 7)) << 4;
    int hi = ((q2 + 1) ^ (lm & 7)) << 4;

    for (int t = 0; t < nt; ++t) {
        unsigned char* Ap = lds + (t & 1) * TILE;
        unsigned char* Bp = lds + BREG + (t & 1) * TILE;
        unsigned char* An = lds + ((t + 1) & 1) * TILE;
        unsigned char* Bn = lds + BREG + ((t + 1) & 1) * TILE;
        bool pre = (t + 1) < nt;

        // ---- phase 1: all 4 B frags + A(mh0); issue B(t+1) ----
#pragma unroll
        for (int n = 0; n < 4; ++n) rd_f8(bfr[n], Bp + bOff + n * 2048, lo, hi);
#pragma unroll
        for (int m = 0; m < 4; ++m) rd_f8(afr[m], Ap + aOff + m * 2048, lo, hi);
        if (pre) {
#pragma unroll
            for (int i = 0; i < 4; ++i)
                __builtin_amdgcn_global_load_lds(AS_GLOBAL(gB[i]), AS_LOCAL(Bn + i * 8192 + wave * 1024), 16, 0, 0);
        }
        __builtin_amdgcn_sched_barrier(0);
        __builtin_amdgcn_s_barrier();
        asm volatile("s_waitcnt lgkmcnt(0)" ::: "memory");
        __builtin_amdgcn_sched_barrier(0);
        __builtin_amdgcn_s_setprio(1);
#pragma unroll
        for (int m = 0; m < 4; ++m)
#pragma unroll
            for (int n = 0; n < 4; ++n)
                acc[m][n] = __builtin_amdgcn_mfma_scale_f32_16x16x128_f8f6f4(
                    afr[m], bfr[n], acc[m][n], 0, 0, 0, 0x7f7f7f7f, 0, 0x7f7f7f7f);
        __builtin_amdgcn_s_setprio(0);
        __builtin_amdgcn_s_barrier();

        // ---- phase 2: A(mh1); issue A(t+1); drain, swap ----
#pragma unroll
        for (int m = 0; m < 4; ++m) rd_f8(afr[m], Ap + aOff + 8192 + m * 2048, lo, hi);
        if (pre) {
#pragma unroll
            for (int i = 0; i < 4; ++i)
                __builtin_amdgcn_global_load_lds(AS_GLOBAL(gA[i]), AS_LOCAL(An + i * 8192 + wave * 1024), 16, 0, 0);
#pragma unroll
            for (int i = 0; i < 4; ++i) { gA[i] += 128; gB[i] += 128; }
        }
        __builtin_amdgcn_sched_barrier(0);
        __builtin_amdgcn_s_barrier();
        asm volatile("s_waitcnt lgkmcnt(0)" ::: "memory");
        __builtin_amdgcn_sched_barrier(0);
        __builtin_amdgcn_s_setprio(1);
#pragma unroll
        for (int m = 0; m < 4; ++m)
#pragma unroll
            for (int n = 0; n < 4; ++n)
                acc[4 + m][n] = __builtin_amdgcn_mfma_scale_f32_16x16x128_f8f6f4(
                    afr[m], bfr[n], acc[4 + m][n], 0, 0, 0, 0x7f7f7f7f, 0, 0x7f7f7f7f);
        __builtin_amdgcn_s_setprio(0);
        asm volatile("s_waitcnt vmcnt(0)" ::: "memory");
        __builtin_amdgcn_s_barrier();
    }

    float biasv[4];
#pragma unroll
    for (int n = 0; n < 4; ++n)
        biasv[n] = BIAS ? bias[tn0 + wni * 64 + n * 16 + lm] : 0.0f;
#pragma unroll
    for (int m = 0; m < 8; ++m) {
#pragma unroll
        for (int n = 0; n < 4; ++n) {
            int gm = tm0 + wmi * 128 + m * 16 + q * 4;
            int gn = tn0 + wni * 64 + n * 16 + lm;
#pragma unroll
            for (int r = 0; r < 4; ++r) {
                float v = acc[m][n][r] * scale;
                if (BIAS) v += biasv[n];
                size_t idx = (size_t)bz * strideC + (size_t)(gm + r) * ldC + gn;
                if (OUTFP8) ((unsigned char*)C)[idx] = f2fp8(v);
                else        ((unsigned short*)C)[idx] = f2b(v);
            }
        }
    }
}

extern "C" void kernel_launch(void* const* d_in, const int* in_sizes, int n_in,
                              void* d_out, int out_size, void* d_ws, size_t ws_size,
                              hipStream_t stream) {
    const float* x    = (const float*)d_in[0];   // [8,2048,1024]
    const int*   mask = (const int*)d_in[1];     // [8,2048,2048]
    const float* Wqkv = (const float*)d_in[2];   // [1024,3072]
    const float* bqkv = (const float*)d_in[3];   // [3072]
    const float* Wout = (const float*)d_in[4];   // [1024,1024]
    const float* bout = (const float*)d_in[5];   // [1024]
    float* out = (float*)d_out;                  // [8,2048,1024]

    char* w = (char*)d_ws;
    unsigned short* x_bf  = (unsigned short*)(w);              // 33,554,432
    unsigned char*  x_f8  = (unsigned char*)(w + 33554432);    // 16,777,216
    unsigned char*  QKf8  = (unsigned char*)(w + 50331648);    // 33,554,432  [16384][2048]: Q cols 0..1023, K cols 1024..2047
    unsigned short* VpT   = (unsigned short*)(w + 117440512);  // 33,554,432  [8][1024][2048]
    unsigned short* S     = (unsigned short*)(w + 150994944);  // 67,108,864
    unsigned char*  WqkT8 = (unsigned char*)(w + 218103808);   //  2,097,152
    unsigned short* WoT   = (unsigned short*)(w + 220200960);  //  2,097,152
    unsigned short* Wv_bf = (unsigned short*)(w + 222298112);  //  2,097,152
    unsigned short* WvoT  = (unsigned short*)(w + 224395264);  //  2,097,152
    float*          bvo   = (float*)(w + 226492416);           //      4,096  -> 226.5 MB total

    // 1) input casts / weight prep
    cast_x<<<16384, 256, 0, stream>>>(x, x_bf, (unsigned int*)x_f8, 4194304);
    transpose_f32_fp8_qk<<<dim3(64, 32), dim3(32, 8), 0, stream>>>(Wqkv, WqkT8);
    transpose_f32_bf16<<<dim3(32, 32), dim3(32, 8), 0, stream>>>(Wout, WoT, 1024, 1024);
    cast_wv<<<1024, 256, 0, stream>>>(Wqkv, Wv_bf);
    bvo_kernel<<<256, 256, 0, stream>>>(WoT, bqkv, bout, bvo);

    // 2) WvoT = (Wv @ Wout)^T : C[e][d] = sum_h WoT[e][h] * Wv[d][h]   (grid 8x8 -> 64)
    gemm_bt<4, false, 0, 3, 3><<<64, 256, 0, stream>>>(
        WoT, 1024, 0, Wv_bf, 1024, 0, WvoT, 1024, 0, nullptr, 1.0f, 1024);

    // 3) QK projection in fp8, 256^2 phase-split: [16384][2048] = x_f8 @ WqkT8^T + bqkv
    gemm_f8_bt8<true, true, 8, 64><<<512, 512, 0, stream>>>(
        x_f8, 1024, 0, WqkT8, 1024, 0, QKf8, 2048, 0, bqkv, 1.0f, 1024);

    // 4) V'^T = (x @ Wvo + bvo)^T, transposed epilogue writes VpT [8][1024][2048] directly
    gemm_bt<5, true, 2, 3, 7><<<1024, 256, 0, stream>>>(
        x_bf, 1024, 0, WvoT, 1024, 0, VpT, 2048, 1024LL * 2048, bvo, 1.0f, 1024);

    // 5) S = Q @ K^T / sqrt(D) in fp8, 256^2 phase-split -> bf16 [8][2048][2048]
    gemm_f8_bt8<false, false, 8, 8><<<512, 512, 0, stream>>>(
        QKf8, 2048, 2048LL * 2048, QKf8 + 1024, 2048, 2048LL * 2048,
        S, 2048, 2048LL * 2048, nullptr, 0.03125f, 1024);

    // 6) softmax -> mask -> softmax, in place
    softmax2_kernel<<<4096, 256, 0, stream>>>(S, mask);

    // 7) out = P @ V' -> fp32 d_out, 256^2 counted-vmcnt kernel (nt = 32 >= 2)
    //    grid 4x8x8 = 256 blocks = 1/CU; XCD k <-> batch k
    gemm_bt8<4, 8><<<256, 512, 0, stream>>>(
        S, 2048, 2048LL * 2048, VpT, 2048, 1024LL * 2048,
        out, 1024, 2048LL * 1024, 1.0f, 2048);
}